// Round 9
// baseline (355.490 us; speedup 1.0000x reference)
//
#include <hip/hip_runtime.h>
#include <hip/hip_fp16.h>

#define DEG 6
#define RC 10
#define NBATCH 2048
#define FDIM 490
#define KPAD 512
#define HID 4096

typedef _Float16 f16x8 __attribute__((ext_vector_type(8)));
typedef _Float16 f16x2 __attribute__((ext_vector_type(2)));
typedef float f32x4 __attribute__((ext_vector_type(4)));

__device__ inline float dot2f(f16x2 x, f16x2 w, float acc) {
#if __has_builtin(__builtin_amdgcn_fdot2)
    return __builtin_amdgcn_fdot2(x, w, acc, false);
#else
    return acc + (float)x[0] * (float)w[0] + (float)x[1] * (float)w[1];
#endif
}

// ---------------- Wigner coefficient tables (device, each call) --------------
__global__ void coef_kernel(float* __restrict__ Ctab) {
    int p = blockIdx.x * blockDim.x + threadIdx.x;
    if (p >= 455) return;
    const int poff[8] = {0, 1, 10, 35, 84, 165, 286, 455};
    const int loff[7] = {0, 1, 28, 153, 496, 1225, 2556};
    int l = 0;
    while (p >= poff[l + 1]) ++l;
    int idx = p - poff[l];
    int nn = 2 * l + 1;
    int mpi = idx / nn, mi = idx % nn;
    int mp = mpi - l, m = mi - l;
    double f[13];
    f[0] = 1.0;
    for (int i = 1; i < 13; ++i) f[i] = f[i - 1] * i;
    double pref = sqrt(f[l + mp] * f[l - mp] * f[l + m] * f[l - m]);
    float* row = Ctab + loff[l] + (size_t)(mpi * nn + mi) * nn;
    for (int q = 0; q < nn; ++q) row[q] = 0.f;
    int s0 = max(0, m - mp), s1 = min(l + m, l - mp);
    for (int s = s0; s <= s1; ++s) {
        int q = mp - m + 2 * s;
        double den = f[l + m - s] * f[s] * f[mp - m + s] * f[l - mp - s];
        double t = pref / den;
        if ((mp - m + s) & 1) t = -t;
        row[q] += (float)t;
    }
}

// ---------------- Wigner D + item projection -> fp16 item[n][512] ------------
__global__ __launch_bounds__(64) void wigner_kernel(
    const float* __restrict__ angles, const float* __restrict__ item_rep,
    const float* __restrict__ Ctab, __half* __restrict__ item_h) {
    int n = blockIdx.x, lane = threadIdx.x;
    float alpha = angles[n * 3 + 0], beta = angles[n * 3 + 1], gamma = angles[n * 3 + 2];
    float cb = cosf(beta * 0.5f), sb = sinf(beta * 0.5f);
    __shared__ float dsh[169], Dsh[169], Psh[13];
    __shared__ float ear[13], eai[13], egr[13], egi[13];
    const int loff[7] = {0, 1, 28, 153, 496, 1225, 2556};
    const float isq = 0.7071067811865476f;
    for (int l = 0; l <= DEG; ++l) {
        int nn = 2 * l + 1;
        if (lane < nn) {
            int q = lane;
            float pv = 1.f;
            for (int i = 0; i < 2 * l - q; ++i) pv *= cb;
            for (int i = 0; i < q; ++i) pv *= sb;
            Psh[q] = pv;
            float mm = (float)(lane - l);
            float sa, ca; sincosf(alpha * mm, &sa, &ca);
            ear[lane] = ca; eai[lane] = -sa;
            float sg, cg; sincosf(gamma * mm, &sg, &cg);
            egr[lane] = cg; egi[lane] = -sg;
        }
        __syncthreads();
        const float* Cl = Ctab + loff[l];
        for (int e = lane; e < nn * nn; e += 64) {
            float acc = 0.f;
            const float* cr = Cl + e * nn;
            for (int q = 0; q < nn; ++q) acc += cr[q] * Psh[q];
            dsh[e] = acc;
        }
        __syncthreads();
        for (int e = lane; e < nn * nn; e += 64) {
            int u = e / nn, v = e - u * nn;
            int bn, bi0, bi1; float br0, br1, bm0, bm1;
            int mu = u - l;
            if (mu == 0)      { bn = 1; bi0 = l; br0 = 1.f; bm0 = 0.f; bi1 = 0; br1 = 0.f; bm1 = 0.f; }
            else if (mu > 0)  { bn = 2; bi0 = l + mu; br0 = (mu & 1) ? -isq : isq; bm0 = 0.f;
                                bi1 = l - mu; br1 = isq; bm1 = 0.f; }
            else              { int mm2 = -mu; bn = 2; bi0 = l - mm2; br0 = 0.f; bm0 = isq;
                                bi1 = l + mm2; br1 = 0.f; bm1 = (mm2 & 1) ? isq : -isq; }
            int cn, ci0, ci1; float cr0, cr1, cm0, cm1;
            int nu = v - l;
            if (nu == 0)      { cn = 1; ci0 = l; cr0 = 1.f; cm0 = 0.f; ci1 = 0; cr1 = 0.f; cm1 = 0.f; }
            else if (nu > 0)  { cn = 2; ci0 = l + nu; cr0 = (nu & 1) ? -isq : isq; cm0 = 0.f;
                                ci1 = l - nu; cr1 = isq; cm1 = 0.f; }
            else              { int mm2 = -nu; cn = 2; ci0 = l - mm2; cr0 = 0.f; cm0 = -isq;
                                ci1 = l + mm2; cr1 = 0.f; cm1 = (mm2 & 1) ? -isq : isq; }
            float acc = 0.f;
            #pragma unroll
            for (int pb = 0; pb < 2; ++pb) {
                if (pb >= bn) break;
                int b = pb ? bi1 : bi0;
                float sr = pb ? br1 : br0, si = pb ? bm1 : bm0;
                float z1r = sr * ear[b] - si * eai[b];
                float z1i = sr * eai[b] + si * ear[b];
                #pragma unroll
                for (int pc = 0; pc < 2; ++pc) {
                    if (pc >= cn) break;
                    int c = pc ? ci1 : ci0;
                    float tr = pc ? cr1 : cr0, ti = pc ? cm1 : cm0;
                    float dv = dsh[b * nn + c];
                    float z2r = egr[c] * tr - egi[c] * ti;
                    float z2i = egr[c] * ti + egi[c] * tr;
                    acc += dv * (z1r * z2r - z1i * z2i);
                }
            }
            Dsh[e] = acc;
        }
        __syncthreads();
        for (int e = lane; e < nn * RC; e += 64) {
            int u = e / RC, r = e - u * RC;
            float acc = 0.f;
            for (int v = 0; v < nn; ++v)
                acc += Dsh[u * nn + v] * item_rep[(l * l + v) * RC + r];
            item_h[(size_t)n * KPAD + (l * l + u) * RC + r] = __float2half(acc);
        }
        __syncthreads();
    }
    if (lane < KPAD - FDIM)
        item_h[(size_t)n * KPAD + FDIM + lane] = __float2half(0.f);
}

// ------- FC weight prep (tiled transpose): W[490,4096] f32 -> Wt[4096][512] f16
__global__ __launch_bounds__(256) void fcw_prep2(const float* __restrict__ W,
                                                 __half* __restrict__ Wt) {
    __shared__ _Float16 tile[64][72];
    int k0 = blockIdx.x * 64;
    int o0 = blockIdx.y * 64;
    int tid = threadIdx.x;
    int tx = tid & 63, ty = tid >> 6;
    #pragma unroll
    for (int i = 0; i < 16; ++i) {
        int k = k0 + ty + i * 4;
        float v = (k < FDIM) ? W[(size_t)k * HID + o0 + tx] : 0.f;
        tile[ty + i * 4][tx] = (_Float16)v;
    }
    __syncthreads();
    #pragma unroll
    for (int p = 0; p < 2; ++p) {
        int idx = tid + p * 256;
        int ol = idx >> 3;
        int kl = (idx & 7) * 8;
        f16x8 v;
        #pragma unroll
        for (int e = 0; e < 8; ++e) v[e] = tile[kl + e][ol];
        *(f16x8*)(Wt + (size_t)(o0 + ol) * KPAD + k0 + kl) = v;
    }
}

// ---- conv weight prep: K[4][4][CIN][COUT] f32 -> Bt[par][COUT][4*CIN] f16 ---
template <int CIN, int COUT>
__global__ __launch_bounds__(256) void convw_prep(const float* __restrict__ K,
                                                  __half* __restrict__ Bt) {
    int par = blockIdx.x >> 2, tap = blockIdx.x & 3;
    int pi = par & 1, pj = par >> 1;
    int t1 = tap >> 1, t2 = tap & 1;
    int dh = pi + 2 * t1, dw = pj + 2 * t2;
    const float* Ks = K + (size_t)(dh * 4 + dw) * CIN * COUT;
    int o = threadIdx.x % COUT;
    int cg = threadIdx.x / COUT;
    constexpr int NG = 256 / COUT;
    for (int c0 = cg * 8; c0 < CIN; c0 += NG * 8) {
        f16x8 v;
        #pragma unroll
        for (int e = 0; e < 8; ++e) v[e] = (_Float16)Ks[(size_t)(c0 + e) * COUT + o];
        *(f16x8*)(Bt + ((size_t)par * COUT + o) * (4 * CIN) + tap * CIN + c0) = v;
    }
}

// ---- conv4 weight prep: K[4][4][32][1] f32 -> f16 [16][32] ------------------
__global__ __launch_bounds__(256) void conv4w_prep(const float* __restrict__ K,
                                                   __half* __restrict__ Kh) {
    int t = blockIdx.x * blockDim.x + threadIdx.x;
    if (t < 512) Kh[t] = __float2half(K[t]);
}

// ---------------- FC as MFMA GEMM: [2048x512] x [512x4096] + relu -> f16 -----
__global__ __launch_bounds__(256) void fc_mfma(
    const __half* __restrict__ A, const __half* __restrict__ Wt,
    const float* __restrict__ bias, __half* __restrict__ Y) {
    int lane = threadIdx.x & 63, wid = threadIdx.x >> 6;
    int job = blockIdx.x * 4 + wid;
    int mbase = job * 32;
    int cb = blockIdx.y * 128;
    int klane = (lane >> 4) * 8, coll = lane & 15;
    const __half* pA0 = A + (size_t)(mbase + coll) * KPAD + klane;
    const __half* pB0 = Wt + (size_t)(cb + coll) * KPAD + klane;
    f32x4 acc[2][8] = {};
    for (int s = 0; s < 16; ++s) {
        f16x8 a0 = *(const f16x8*)(pA0 + s * 32);
        f16x8 a1 = *(const f16x8*)(pA0 + 16 * KPAD + s * 32);
        #pragma unroll
        for (int f = 0; f < 8; ++f) {
            f16x8 b = *(const f16x8*)(pB0 + (size_t)f * 16 * KPAD + s * 32);
            acc[0][f] = __builtin_amdgcn_mfma_f32_16x16x32_f16(a0, b, acc[0][f], 0, 0, 0);
            acc[1][f] = __builtin_amdgcn_mfma_f32_16x16x32_f16(a1, b, acc[1][f], 0, 0, 0);
        }
    }
    #pragma unroll
    for (int f = 0; f < 8; ++f) {
        float bv = bias[cb + f * 16 + coll];
        #pragma unroll
        for (int r = 0; r < 2; ++r)
            #pragma unroll
            for (int g = 0; g < 4; ++g) {
                int m = mbase + r * 16 + (lane >> 4) * 4 + g;
                float v = acc[r][f][g] + bv;
                v = v > 0.f ? v : 0.f;
                Y[(size_t)m * HID + cb + f * 16 + coll] = __float2half(v);
            }
    }
}

// ------- conv_transpose: A + double-buffered B both in LDS, serial parity ----
template <int CIN, int COUT, int HIN, int R, int LOGH, int CF, int WAVES, int KSPLIT, int OH, int OB>
__global__ __launch_bounds__(WAVES * 64) void convt_lds3(
    const __half* __restrict__ X, const __half* __restrict__ Bt,
    const float* __restrict__ bias, __half* __restrict__ Y) {
    constexpr int HH = HIN * HIN;
    constexpr int KTOT = 4 * CIN;
    constexpr int CINS = CIN / KSPLIT;     // k-width per stage
    constexpr int NSTEPS = CINS / 32;      // k-chunks per stage
    constexpr int SL = CIN / 8;            // A 16B slots per row
    constexpr int SLB = CINS / 8;          // B 16B slots per row
    constexpr int T = WAVES * 64;
    constexpr int POS = WAVES * R * 16;    // positions (= A rows) per block
    constexpr int AROWS = POS;
    constexpr int AH = AROWS * CIN;        // halves
    constexpr int BROWS = CF * 16;
    constexpr int BH = BROWS * CINS;       // halves per B buffer
    constexpr int SA = AROWS * SL;
    constexpr int SB = BROWS * SLB;
    constexpr int NSB = SB / T;
    constexpr int NST = 16 * KSPLIT;       // total stages
    __shared__ _Float16 lds[AH + 2 * BH];

    int tid = threadIdx.x;
    int lane = tid & 63, w = tid >> 6;
    int kg = lane >> 4, coll = lane & 15;
    int n0 = blockIdx.x * (POS >> (2 * LOGH));
    int cbase = blockIdx.y * (CF * 16);
    int posbase = w * (R * 16);

    // ---- stage A (coalesced global -> swizzled LDS) ----
    const __half* Xs = X + (size_t)n0 * HH * CIN;
    #pragma unroll
    for (int q = 0; q < SA / T; ++q) {
        int i = tid + q * T;
        int row = i / SL, slot = i % SL;
        f16x8 v = *(const f16x8*)(Xs + (size_t)i * 8);
        *(f16x8*)(&lds[row * CIN + ((slot ^ (row & 7)) * 8)]) = v;
    }
    // ---- stage B for stage 0 into buffer 0 ----
    f16x8 breg[NSB];
    #pragma unroll
    for (int q = 0; q < NSB; ++q) {
        int i = tid + q * T;
        int o = i / SLB, sl = i % SLB;
        breg[q] = *(const f16x8*)(Bt + ((size_t)(cbase + o) * KTOT) + sl * 8);
    }
    #pragma unroll
    for (int q = 0; q < NSB; ++q) {
        int i = tid + q * T;
        int o = i / SLB, sl = i % SLB;
        *(f16x8*)(&lds[AH + o * CINS + ((sl ^ (o & 7)) * 8)]) = breg[q];
    }
    __syncthreads();

    int posl[R]; bool okr[R][3], okc[R][3];
    #pragma unroll
    for (int r = 0; r < R; ++r) {
        int p = posbase + r * 16 + coll;
        posl[r] = p;
        int rem = p & (HH - 1);
        int a = rem >> LOGH, b = rem & (HIN - 1);
        #pragma unroll
        for (int s = 0; s < 3; ++s) {
            okr[r][s] = (unsigned)(a + s - 1) < (unsigned)HIN;
            okc[r][s] = (unsigned)(b + s - 1) < (unsigned)HIN;
        }
    }

    float bvv[CF];
    #pragma unroll
    for (int f = 0; f < CF; ++f) bvv[f] = bias[cbase + f * 16 + coll];

    #pragma unroll
    for (int par = 0; par < 4; ++par) {
        const int pi = par & 1, pj = par >> 1;
        f32x4 acc[R][CF];
        #pragma unroll
        for (int r = 0; r < R; ++r)
            #pragma unroll
            for (int f = 0; f < CF; ++f)
                acc[r][f] = (f32x4){bvv[f], bvv[f], bvv[f], bvv[f]};

        #pragma unroll
        for (int tt = 0; tt < 4 * KSPLIT; ++tt) {
            const int s = par * 4 * KSPLIT + tt;
            const int tap = tt / KSPLIT;
            const int kh = tt % KSPLIT;
            const int buf = s & 1;
            // issue next stage's B loads early (hide HBM/L2 latency under MFMA)
            if (s + 1 < NST) {
                const int s2 = s + 1;
                const int par2 = s2 / (4 * KSPLIT);
                const int tt2 = s2 % (4 * KSPLIT);
                const int tap2 = tt2 / KSPLIT;
                const int kh2 = tt2 % KSPLIT;
                #pragma unroll
                for (int q = 0; q < NSB; ++q) {
                    int i = tid + q * T;
                    int o = i / SLB, sl = i % SLB;
                    breg[q] = *(const f16x8*)(Bt +
                        ((size_t)(par2 * COUT + cbase + o) * KTOT +
                         tap2 * CIN + kh2 * CINS) + sl * 8);
                }
            }
            // compute stage s
            const int iu = (tap >> 1) + pi, iv = (tap & 1) + pj;
            const int delta = (iu - 1) * HIN + (iv - 1);
            int rp[R]; bool ok[R];
            #pragma unroll
            for (int r = 0; r < R; ++r) {
                int t = posl[r] + delta;
                rp[r] = min(max(t, 0), AROWS - 1);
                ok[r] = okr[r][iu] && okc[r][iv];
            }
            const _Float16* Bl = &lds[AH + buf * BH];
            #pragma unroll
            for (int cc = 0; cc < NSTEPS; ++cc) {
                const int slB = cc * 4 + kg;
                const int slA = kh * SLB + slB;
                f16x8 b[CF];
                #pragma unroll
                for (int f = 0; f < CF; ++f)
                    b[f] = *(const f16x8*)(&Bl[(f * 16 + coll) * CINS +
                                               ((slB ^ (coll & 7)) * 8)]);
                f16x8 a[R];
                #pragma unroll
                for (int r = 0; r < R; ++r) {
                    f16x8 v = *(const f16x8*)(&lds[rp[r] * CIN +
                                                   ((slA ^ (rp[r] & 7)) * 8)]);
                    a[r] = ok[r] ? v : (f16x8){0, 0, 0, 0, 0, 0, 0, 0};
                }
                #pragma unroll
                for (int r = 0; r < R; ++r)
                    #pragma unroll
                    for (int f = 0; f < CF; ++f)
                        acc[r][f] = __builtin_amdgcn_mfma_f32_16x16x32_f16(
                            a[r], b[f], acc[r][f], 0, 0, 0);
            }
            // write-late into the other buffer, one barrier per stage
            if (s + 1 < NST) {
                #pragma unroll
                for (int q = 0; q < NSB; ++q) {
                    int i = tid + q * T;
                    int o = i / SLB, sl = i % SLB;
                    *(f16x8*)(&lds[AH + ((s + 1) & 1) * BH + o * CINS +
                                   ((sl ^ (o & 7)) * 8)]) = breg[q];
                }
                __syncthreads();
            }
        }

        // ---- epilogue for this parity ----
        #pragma unroll
        for (int r = 0; r < R; ++r) {
            #pragma unroll
            for (int g = 0; g < 4; ++g) {
                int p = posbase + r * 16 + kg * 4 + g;
                int ni = p >> (2 * LOGH);
                int rem = p & (HH - 1);
                int a2 = rem >> LOGH, b2 = rem & (HIN - 1);
                size_t ob = (((size_t)(n0 + ni) * OH + 2 * a2 + pi + OB) * OH +
                             2 * b2 + pj + OB) * COUT;
                #pragma unroll
                for (int f = 0; f < CF; ++f) {
                    float v = acc[r][f][g];
                    v = v > 0.f ? v : 0.f;
                    Y[ob + cbase + f * 16 + coll] = __float2half(v);
                }
            }
        }
    }
}

// ---------------- zero the 1-wide border ring of padded x3 -------------------
__global__ __launch_bounds__(256) void pad_zero(__half* __restrict__ Xp) {
    int n = blockIdx.x;
    __half* base = Xp + (size_t)n * 34 * 34 * 32;
    for (int w = threadIdx.x; w < 132 * 4; w += 256) {
        int posi = w >> 2, q = w & 3;
        int r, s;
        if (posi < 68) { r = (posi < 34) ? 0 : 33; s = posi % 34; }
        else { int e = posi - 68; r = 1 + (e >> 1); s = (e & 1) ? 33 : 0; }
        *(f16x8*)(base + ((size_t)r * 34 + s) * 32 + q * 8) = (f16x8){0, 0, 0, 0, 0, 0, 0, 0};
    }
}

// ------- conv4 v3: 2x2-site register blocking, one block per image -----------
// Thread owns sites (sa..sa+1, sb..sb+1) = 16 outputs from a 4x4 input window;
// 4 channel-chunks of 8; weights one row at a time (each (dh,dw) row feeds
// exactly one (parity,tap) combo); 4x contiguous float4 stores.
__global__ __launch_bounds__(256) void conv4_kernel3(
    const __half* __restrict__ Xp, const __half* __restrict__ Wh,
    const float* __restrict__ bias, float* __restrict__ out) {
    int n = blockIdx.x;
    int t = threadIdx.x;
    int tx = t & 15, ty = t >> 4;
    int sa = ty * 2, sb = tx * 2;      // site-block origin (sites 0..31)
    const __half* Xn = Xp + ((size_t)n * 34 * 34 + (size_t)sa * 34 + sb) * 32;
    float bv = bias[0];
    float accr[4][4];                  // [2i+pi][2j+pj]
    #pragma unroll
    for (int r = 0; r < 4; ++r)
        #pragma unroll
        for (int c = 0; c < 4; ++c) accr[r][c] = bv;

    #pragma unroll
    for (int ch = 0; ch < 4; ++ch) {
        f16x8 win[4][4];
        #pragma unroll
        for (int u = 0; u < 4; ++u)
            #pragma unroll
            for (int v = 0; v < 4; ++v)
                win[u][v] = *(const f16x8*)(Xn + ((size_t)u * 34 + v) * 32 + ch * 8);
        #pragma unroll
        for (int dh = 0; dh < 4; ++dh) {
            #pragma unroll
            for (int dw = 0; dw < 4; ++dw) {
                f16x8 w8 = *(const f16x8*)(Wh + (dh * 4 + dw) * 32 + ch * 8);
                const int pi = dh & 1, t1 = dh >> 1;
                const int pj = dw & 1, t2 = dw >> 1;
                #pragma unroll
                for (int i = 0; i < 2; ++i)
                    #pragma unroll
                    for (int j = 0; j < 2; ++j) {
                        f16x8 x8 = win[i + pi + t1][j + pj + t2];
                        float a = accr[2 * i + pi][2 * j + pj];
                        #pragma unroll
                        for (int e = 0; e < 4; ++e)
                            a = dot2f((f16x2){x8[2 * e], x8[2 * e + 1]},
                                      (f16x2){w8[2 * e], w8[2 * e + 1]}, a);
                        accr[2 * i + pi][2 * j + pj] = a;
                    }
            }
        }
    }
    #pragma unroll
    for (int r = 0; r < 4; ++r) {
        float4 v = {accr[r][0], accr[r][1], accr[r][2], accr[r][3]};
        *(float4*)(&out[((size_t)n * 64 + 2 * sa + r) * 64 + 2 * sb]) = v;
    }
}

// ---------------- launch -----------------------------------------------------
extern "C" void kernel_launch(void* const* d_in, const int* in_sizes, int n_in,
                              void* d_out, int out_size, void* d_ws, size_t ws_size,
                              hipStream_t stream) {
    const float* angles   = (const float*)d_in[0];
    const float* item_rep = (const float*)d_in[1];
    const float* W        = (const float*)d_in[2];
    const float* bfc      = (const float*)d_in[3];
    const float* k1       = (const float*)d_in[4];
    const float* b1       = (const float*)d_in[5];
    const float* k2       = (const float*)d_in[6];
    const float* b2       = (const float*)d_in[7];
    const float* k3       = (const float*)d_in[8];
    const float* b3       = (const float*)d_in[9];
    const float* k4       = (const float*)d_in[10];
    const float* b4       = (const float*)d_in[11];

    char* ws = (char*)d_ws;
    float*  Ctab  = (float*)(ws + 0);                 //  32 KB
    __half* itemh = (__half*)(ws + 32768);            //   2 MB
    __half* Bt1   = (__half*)(ws + 2129920);          //   1 MB
    __half* Bt2   = (__half*)(ws + 3178496);          // 256 KB
    __half* Bt3   = (__half*)(ws + 3440640);          //  64 KB
    __half* Kh4   = (__half*)(ws + 3506176);          //   1 KB
    __half* x0    = (__half*)(ws + 4194304);          //  16 MB -> 20,971,520
    __half* x1    = (__half*)(ws + 20971520);         //  32 MB -> 54,525,952
    __half* x3p   = (__half*)(ws + 4194304);          // 151.5 MB -> 155,713,536
    __half* Wtfc  = (__half*)(ws + 121634816);        //   4 MB (inside x3p, dead by conv3)
    __half* x2    = (__half*)(ws + 155713536);        //  64 MB -> 222,822,400
    float*  out   = (float*)d_out;

    coef_kernel<<<1, 512, 0, stream>>>(Ctab);
    wigner_kernel<<<NBATCH, 64, 0, stream>>>(angles, item_rep, Ctab, itemh);
    fcw_prep2<<<dim3(KPAD / 64, HID / 64), 256, 0, stream>>>(W, Wtfc);
    convw_prep<256, 128><<<16, 256, 0, stream>>>(k1, Bt1);
    convw_prep<128, 64><<<16, 256, 0, stream>>>(k2, Bt2);
    convw_prep<64, 32><<<16, 256, 0, stream>>>(k3, Bt3);
    conv4w_prep<<<2, 256, 0, stream>>>(k4, Kh4);

    // FC: 2048x512 @ 512x4096 -> x0
    fc_mfma<<<dim3(16, 32), 256, 0, stream>>>(itemh, Wtfc, bfc, x0);
    // conv1: 4x4x256 -> 8x8x128  (R=1, CF=4, y=2 slices, k-split B stages)
    convt_lds3<256, 128, 4, 1, 2, 4, 4, 2, 8, 0><<<dim3(512, 2), 256, 0, stream>>>(x0, Bt1, b1, x1);
    // conv2: 8x8x128 -> 16x16x64 (R=2, CF=4) LDS = 32+32 = 64KB
    convt_lds3<128, 64, 8, 2, 3, 4, 4, 1, 16, 0><<<dim3(1024, 1), 256, 0, stream>>>(x1, Bt2, b2, x2);
    // zero x3p border ring, then conv3 writes the 32x32 interior at +1
    pad_zero<<<NBATCH, 256, 0, stream>>>(x3p);
    // conv3: 16x16x64 -> (34x34 padded)x32 (R=4, CF=2) LDS = 32+8 = 40KB
    convt_lds3<64, 32, 16, 4, 4, 2, 4, 1, 34, 1><<<dim3(2048, 1), 256, 0, stream>>>(x2, Bt3, b3, x3p);
    // conv4 v3: padded 34x34x32 -> 64x64x1 (fp32 out), 2x2-site blocking
    conv4_kernel3<<<NBATCH, 256, 0, stream>>>(x3p, Kh4, b4, out);
}

// Round 10
// 339.421 us; speedup vs baseline: 1.0473x; 1.0473x over previous
//
#include <hip/hip_runtime.h>
#include <hip/hip_fp16.h>

#define DEG 6
#define RC 10
#define NBATCH 2048
#define FDIM 490
#define KPAD 512
#define HID 4096

typedef _Float16 f16x8 __attribute__((ext_vector_type(8)));
typedef _Float16 f16x2 __attribute__((ext_vector_type(2)));
typedef float f32x4 __attribute__((ext_vector_type(4)));

__device__ inline float dot2f(f16x2 x, f16x2 w, float acc) {
#if __has_builtin(__builtin_amdgcn_fdot2)
    return __builtin_amdgcn_fdot2(x, w, acc, false);
#else
    return acc + (float)x[0] * (float)w[0] + (float)x[1] * (float)w[1];
#endif
}

// ---------------- Wigner coefficient tables (device, each call) --------------
__global__ void coef_kernel(float* __restrict__ Ctab) {
    int p = blockIdx.x * blockDim.x + threadIdx.x;
    if (p >= 455) return;
    const int poff[8] = {0, 1, 10, 35, 84, 165, 286, 455};
    const int loff[7] = {0, 1, 28, 153, 496, 1225, 2556};
    int l = 0;
    while (p >= poff[l + 1]) ++l;
    int idx = p - poff[l];
    int nn = 2 * l + 1;
    int mpi = idx / nn, mi = idx % nn;
    int mp = mpi - l, m = mi - l;
    double f[13];
    f[0] = 1.0;
    for (int i = 1; i < 13; ++i) f[i] = f[i - 1] * i;
    double pref = sqrt(f[l + mp] * f[l - mp] * f[l + m] * f[l - m]);
    float* row = Ctab + loff[l] + (size_t)(mpi * nn + mi) * nn;
    for (int q = 0; q < nn; ++q) row[q] = 0.f;
    int s0 = max(0, m - mp), s1 = min(l + m, l - mp);
    for (int s = s0; s <= s1; ++s) {
        int q = mp - m + 2 * s;
        double den = f[l + m - s] * f[s] * f[mp - m + s] * f[l - mp - s];
        double t = pref / den;
        if ((mp - m + s) & 1) t = -t;
        row[q] += (float)t;
    }
}

// ---------------- Wigner D + item projection -> fp16 item[n][512] ------------
__global__ __launch_bounds__(64) void wigner_kernel(
    const float* __restrict__ angles, const float* __restrict__ item_rep,
    const float* __restrict__ Ctab, __half* __restrict__ item_h) {
    int n = blockIdx.x, lane = threadIdx.x;
    float alpha = angles[n * 3 + 0], beta = angles[n * 3 + 1], gamma = angles[n * 3 + 2];
    float cb = cosf(beta * 0.5f), sb = sinf(beta * 0.5f);
    __shared__ float dsh[169], Dsh[169], Psh[13];
    __shared__ float ear[13], eai[13], egr[13], egi[13];
    const int loff[7] = {0, 1, 28, 153, 496, 1225, 2556};
    const float isq = 0.7071067811865476f;
    for (int l = 0; l <= DEG; ++l) {
        int nn = 2 * l + 1;
        if (lane < nn) {
            int q = lane;
            float pv = 1.f;
            for (int i = 0; i < 2 * l - q; ++i) pv *= cb;
            for (int i = 0; i < q; ++i) pv *= sb;
            Psh[q] = pv;
            float mm = (float)(lane - l);
            float sa, ca; sincosf(alpha * mm, &sa, &ca);
            ear[lane] = ca; eai[lane] = -sa;
            float sg, cg; sincosf(gamma * mm, &sg, &cg);
            egr[lane] = cg; egi[lane] = -sg;
        }
        __syncthreads();
        const float* Cl = Ctab + loff[l];
        for (int e = lane; e < nn * nn; e += 64) {
            float acc = 0.f;
            const float* cr = Cl + e * nn;
            for (int q = 0; q < nn; ++q) acc += cr[q] * Psh[q];
            dsh[e] = acc;
        }
        __syncthreads();
        for (int e = lane; e < nn * nn; e += 64) {
            int u = e / nn, v = e - u * nn;
            int bn, bi0, bi1; float br0, br1, bm0, bm1;
            int mu = u - l;
            if (mu == 0)      { bn = 1; bi0 = l; br0 = 1.f; bm0 = 0.f; bi1 = 0; br1 = 0.f; bm1 = 0.f; }
            else if (mu > 0)  { bn = 2; bi0 = l + mu; br0 = (mu & 1) ? -isq : isq; bm0 = 0.f;
                                bi1 = l - mu; br1 = isq; bm1 = 0.f; }
            else              { int mm2 = -mu; bn = 2; bi0 = l - mm2; br0 = 0.f; bm0 = isq;
                                bi1 = l + mm2; br1 = 0.f; bm1 = (mm2 & 1) ? isq : -isq; }
            int cn, ci0, ci1; float cr0, cr1, cm0, cm1;
            int nu = v - l;
            if (nu == 0)      { cn = 1; ci0 = l; cr0 = 1.f; cm0 = 0.f; ci1 = 0; cr1 = 0.f; cm1 = 0.f; }
            else if (nu > 0)  { cn = 2; ci0 = l + nu; cr0 = (nu & 1) ? -isq : isq; cm0 = 0.f;
                                ci1 = l - nu; cr1 = isq; cm1 = 0.f; }
            else              { int mm2 = -nu; cn = 2; ci0 = l - mm2; cr0 = 0.f; cm0 = -isq;
                                ci1 = l + mm2; cr1 = 0.f; cm1 = (mm2 & 1) ? -isq : isq; }
            float acc = 0.f;
            #pragma unroll
            for (int pb = 0; pb < 2; ++pb) {
                if (pb >= bn) break;
                int b = pb ? bi1 : bi0;
                float sr = pb ? br1 : br0, si = pb ? bm1 : bm0;
                float z1r = sr * ear[b] - si * eai[b];
                float z1i = sr * eai[b] + si * ear[b];
                #pragma unroll
                for (int pc = 0; pc < 2; ++pc) {
                    if (pc >= cn) break;
                    int c = pc ? ci1 : ci0;
                    float tr = pc ? cr1 : cr0, ti = pc ? cm1 : cm0;
                    float dv = dsh[b * nn + c];
                    float z2r = egr[c] * tr - egi[c] * ti;
                    float z2i = egr[c] * ti + egi[c] * tr;
                    acc += dv * (z1r * z2r - z1i * z2i);
                }
            }
            Dsh[e] = acc;
        }
        __syncthreads();
        for (int e = lane; e < nn * RC; e += 64) {
            int u = e / RC, r = e - u * RC;
            float acc = 0.f;
            for (int v = 0; v < nn; ++v)
                acc += Dsh[u * nn + v] * item_rep[(l * l + v) * RC + r];
            item_h[(size_t)n * KPAD + (l * l + u) * RC + r] = __float2half(acc);
        }
        __syncthreads();
    }
    if (lane < KPAD - FDIM)
        item_h[(size_t)n * KPAD + FDIM + lane] = __float2half(0.f);
}

// ------- FC weight prep (tiled transpose): W[490,4096] f32 -> Wt[4096][512] f16
__global__ __launch_bounds__(256) void fcw_prep2(const float* __restrict__ W,
                                                 __half* __restrict__ Wt) {
    __shared__ _Float16 tile[64][72];
    int k0 = blockIdx.x * 64;
    int o0 = blockIdx.y * 64;
    int tid = threadIdx.x;
    int tx = tid & 63, ty = tid >> 6;
    #pragma unroll
    for (int i = 0; i < 16; ++i) {
        int k = k0 + ty + i * 4;
        float v = (k < FDIM) ? W[(size_t)k * HID + o0 + tx] : 0.f;
        tile[ty + i * 4][tx] = (_Float16)v;
    }
    __syncthreads();
    #pragma unroll
    for (int p = 0; p < 2; ++p) {
        int idx = tid + p * 256;
        int ol = idx >> 3;
        int kl = (idx & 7) * 8;
        f16x8 v;
        #pragma unroll
        for (int e = 0; e < 8; ++e) v[e] = tile[kl + e][ol];
        *(f16x8*)(Wt + (size_t)(o0 + ol) * KPAD + k0 + kl) = v;
    }
}

// ---- conv weight prep: K[4][4][CIN][COUT] f32 -> Bt[par][COUT][4*CIN] f16 ---
template <int CIN, int COUT>
__global__ __launch_bounds__(256) void convw_prep(const float* __restrict__ K,
                                                  __half* __restrict__ Bt) {
    int par = blockIdx.x >> 2, tap = blockIdx.x & 3;
    int pi = par & 1, pj = par >> 1;
    int t1 = tap >> 1, t2 = tap & 1;
    int dh = pi + 2 * t1, dw = pj + 2 * t2;
    const float* Ks = K + (size_t)(dh * 4 + dw) * CIN * COUT;
    int o = threadIdx.x % COUT;
    int cg = threadIdx.x / COUT;
    constexpr int NG = 256 / COUT;
    for (int c0 = cg * 8; c0 < CIN; c0 += NG * 8) {
        f16x8 v;
        #pragma unroll
        for (int e = 0; e < 8; ++e) v[e] = (_Float16)Ks[(size_t)(c0 + e) * COUT + o];
        *(f16x8*)(Bt + ((size_t)par * COUT + o) * (4 * CIN) + tap * CIN + c0) = v;
    }
}

// ---- conv4 weight prep: K[4][4][32][1] f32 -> f16 [16][32] ------------------
__global__ __launch_bounds__(256) void conv4w_prep(const float* __restrict__ K,
                                                   __half* __restrict__ Kh) {
    int t = blockIdx.x * blockDim.x + threadIdx.x;
    if (t < 512) Kh[t] = __float2half(K[t]);
}

// ---------------- FC as MFMA GEMM: [2048x512] x [512x4096] + relu -> f16 -----
__global__ __launch_bounds__(256) void fc_mfma(
    const __half* __restrict__ A, const __half* __restrict__ Wt,
    const float* __restrict__ bias, __half* __restrict__ Y) {
    int lane = threadIdx.x & 63, wid = threadIdx.x >> 6;
    int job = blockIdx.x * 4 + wid;
    int mbase = job * 32;
    int cb = blockIdx.y * 128;
    int klane = (lane >> 4) * 8, coll = lane & 15;
    const __half* pA0 = A + (size_t)(mbase + coll) * KPAD + klane;
    const __half* pB0 = Wt + (size_t)(cb + coll) * KPAD + klane;
    f32x4 acc[2][8] = {};
    for (int s = 0; s < 16; ++s) {
        f16x8 a0 = *(const f16x8*)(pA0 + s * 32);
        f16x8 a1 = *(const f16x8*)(pA0 + 16 * KPAD + s * 32);
        #pragma unroll
        for (int f = 0; f < 8; ++f) {
            f16x8 b = *(const f16x8*)(pB0 + (size_t)f * 16 * KPAD + s * 32);
            acc[0][f] = __builtin_amdgcn_mfma_f32_16x16x32_f16(a0, b, acc[0][f], 0, 0, 0);
            acc[1][f] = __builtin_amdgcn_mfma_f32_16x16x32_f16(a1, b, acc[1][f], 0, 0, 0);
        }
    }
    #pragma unroll
    for (int f = 0; f < 8; ++f) {
        float bv = bias[cb + f * 16 + coll];
        #pragma unroll
        for (int r = 0; r < 2; ++r)
            #pragma unroll
            for (int g = 0; g < 4; ++g) {
                int m = mbase + r * 16 + (lane >> 4) * 4 + g;
                float v = acc[r][f][g] + bv;
                v = v > 0.f ? v : 0.f;
                Y[(size_t)m * HID + cb + f * 16 + coll] = __float2half(v);
            }
    }
}

// ------- conv_transpose: A + double-buffered B both in LDS, serial parity ----
// SPLITC=1: output layout [n][f-plane(CF)][site(OH*OH)][16ch] (for conv4 staging).
template <int CIN, int COUT, int HIN, int R, int LOGH, int CF, int WAVES, int KSPLIT, int OH, int OB, int SPLITC>
__global__ __launch_bounds__(WAVES * 64) void convt_lds3(
    const __half* __restrict__ X, const __half* __restrict__ Bt,
    const float* __restrict__ bias, __half* __restrict__ Y) {
    constexpr int HH = HIN * HIN;
    constexpr int KTOT = 4 * CIN;
    constexpr int CINS = CIN / KSPLIT;     // k-width per stage
    constexpr int NSTEPS = CINS / 32;      // k-chunks per stage
    constexpr int SL = CIN / 8;            // A 16B slots per row
    constexpr int SLB = CINS / 8;          // B 16B slots per row
    constexpr int T = WAVES * 64;
    constexpr int POS = WAVES * R * 16;    // positions (= A rows) per block
    constexpr int AROWS = POS;
    constexpr int AH = AROWS * CIN;        // halves
    constexpr int BROWS = CF * 16;
    constexpr int BH = BROWS * CINS;       // halves per B buffer
    constexpr int SA = AROWS * SL;
    constexpr int SB = BROWS * SLB;
    constexpr int NSB = SB / T;
    constexpr int NST = 16 * KSPLIT;       // total stages
    __shared__ _Float16 lds[AH + 2 * BH];

    int tid = threadIdx.x;
    int lane = tid & 63, w = tid >> 6;
    int kg = lane >> 4, coll = lane & 15;
    int n0 = blockIdx.x * (POS >> (2 * LOGH));
    int cbase = blockIdx.y * (CF * 16);
    int posbase = w * (R * 16);

    // ---- stage A (coalesced global -> swizzled LDS) ----
    const __half* Xs = X + (size_t)n0 * HH * CIN;
    #pragma unroll
    for (int q = 0; q < SA / T; ++q) {
        int i = tid + q * T;
        int row = i / SL, slot = i % SL;
        f16x8 v = *(const f16x8*)(Xs + (size_t)i * 8);
        *(f16x8*)(&lds[row * CIN + ((slot ^ (row & 7)) * 8)]) = v;
    }
    // ---- stage B for stage 0 into buffer 0 ----
    f16x8 breg[NSB];
    #pragma unroll
    for (int q = 0; q < NSB; ++q) {
        int i = tid + q * T;
        int o = i / SLB, sl = i % SLB;
        breg[q] = *(const f16x8*)(Bt + ((size_t)(cbase + o) * KTOT) + sl * 8);
    }
    #pragma unroll
    for (int q = 0; q < NSB; ++q) {
        int i = tid + q * T;
        int o = i / SLB, sl = i % SLB;
        *(f16x8*)(&lds[AH + o * CINS + ((sl ^ (o & 7)) * 8)]) = breg[q];
    }
    __syncthreads();

    int posl[R]; bool okr[R][3], okc[R][3];
    #pragma unroll
    for (int r = 0; r < R; ++r) {
        int p = posbase + r * 16 + coll;
        posl[r] = p;
        int rem = p & (HH - 1);
        int a = rem >> LOGH, b = rem & (HIN - 1);
        #pragma unroll
        for (int s = 0; s < 3; ++s) {
            okr[r][s] = (unsigned)(a + s - 1) < (unsigned)HIN;
            okc[r][s] = (unsigned)(b + s - 1) < (unsigned)HIN;
        }
    }

    float bvv[CF];
    #pragma unroll
    for (int f = 0; f < CF; ++f) bvv[f] = bias[cbase + f * 16 + coll];

    #pragma unroll
    for (int par = 0; par < 4; ++par) {
        const int pi = par & 1, pj = par >> 1;
        f32x4 acc[R][CF];
        #pragma unroll
        for (int r = 0; r < R; ++r)
            #pragma unroll
            for (int f = 0; f < CF; ++f)
                acc[r][f] = (f32x4){bvv[f], bvv[f], bvv[f], bvv[f]};

        #pragma unroll
        for (int tt = 0; tt < 4 * KSPLIT; ++tt) {
            const int s = par * 4 * KSPLIT + tt;
            const int tap = tt / KSPLIT;
            const int kh = tt % KSPLIT;
            const int buf = s & 1;
            // issue next stage's B loads early (hide HBM/L2 latency under MFMA)
            if (s + 1 < NST) {
                const int s2 = s + 1;
                const int par2 = s2 / (4 * KSPLIT);
                const int tt2 = s2 % (4 * KSPLIT);
                const int tap2 = tt2 / KSPLIT;
                const int kh2 = tt2 % KSPLIT;
                #pragma unroll
                for (int q = 0; q < NSB; ++q) {
                    int i = tid + q * T;
                    int o = i / SLB, sl = i % SLB;
                    breg[q] = *(const f16x8*)(Bt +
                        ((size_t)(par2 * COUT + cbase + o) * KTOT +
                         tap2 * CIN + kh2 * CINS) + sl * 8);
                }
            }
            // compute stage s
            const int iu = (tap >> 1) + pi, iv = (tap & 1) + pj;
            const int delta = (iu - 1) * HIN + (iv - 1);
            int rp[R]; bool ok[R];
            #pragma unroll
            for (int r = 0; r < R; ++r) {
                int t = posl[r] + delta;
                rp[r] = min(max(t, 0), AROWS - 1);
                ok[r] = okr[r][iu] && okc[r][iv];
            }
            const _Float16* Bl = &lds[AH + buf * BH];
            #pragma unroll
            for (int cc = 0; cc < NSTEPS; ++cc) {
                const int slB = cc * 4 + kg;
                const int slA = kh * SLB + slB;
                f16x8 b[CF];
                #pragma unroll
                for (int f = 0; f < CF; ++f)
                    b[f] = *(const f16x8*)(&Bl[(f * 16 + coll) * CINS +
                                               ((slB ^ (coll & 7)) * 8)]);
                f16x8 a[R];
                #pragma unroll
                for (int r = 0; r < R; ++r) {
                    f16x8 v = *(const f16x8*)(&lds[rp[r] * CIN +
                                                   ((slA ^ (rp[r] & 7)) * 8)]);
                    a[r] = ok[r] ? v : (f16x8){0, 0, 0, 0, 0, 0, 0, 0};
                }
                #pragma unroll
                for (int r = 0; r < R; ++r)
                    #pragma unroll
                    for (int f = 0; f < CF; ++f)
                        acc[r][f] = __builtin_amdgcn_mfma_f32_16x16x32_f16(
                            a[r], b[f], acc[r][f], 0, 0, 0);
            }
            // write-late into the other buffer, one barrier per stage
            if (s + 1 < NST) {
                #pragma unroll
                for (int q = 0; q < NSB; ++q) {
                    int i = tid + q * T;
                    int o = i / SLB, sl = i % SLB;
                    *(f16x8*)(&lds[AH + ((s + 1) & 1) * BH + o * CINS +
                                   ((sl ^ (o & 7)) * 8)]) = breg[q];
                }
                __syncthreads();
            }
        }

        // ---- epilogue for this parity ----
        #pragma unroll
        for (int r = 0; r < R; ++r) {
            #pragma unroll
            for (int g = 0; g < 4; ++g) {
                int p = posbase + r * 16 + kg * 4 + g;
                int ni = p >> (2 * LOGH);
                int rem = p & (HH - 1);
                int a2 = rem >> LOGH, b2 = rem & (HIN - 1);
                if constexpr (SPLITC) {
                    int site = (2 * a2 + pi + OB) * OH + (2 * b2 + pj + OB);
                    #pragma unroll
                    for (int f = 0; f < CF; ++f) {
                        float v = acc[r][f][g];
                        v = v > 0.f ? v : 0.f;
                        Y[(((size_t)(n0 + ni) * CF + f) * (OH * OH) + site) * 16 + coll] =
                            __float2half(v);
                    }
                } else {
                    size_t ob = (((size_t)(n0 + ni) * OH + 2 * a2 + pi + OB) * OH +
                                 2 * b2 + pj + OB) * COUT;
                    #pragma unroll
                    for (int f = 0; f < CF; ++f) {
                        float v = acc[r][f][g];
                        v = v > 0.f ? v : 0.f;
                        Y[ob + cbase + f * 16 + coll] = __float2half(v);
                    }
                }
            }
        }
    }
}

// ------- zero the border ring of plane-split x3p [n][2][1156][16] ------------
__global__ __launch_bounds__(256) void pad_zero2(__half* __restrict__ Xp) {
    int n = blockIdx.x;
    __half* base = Xp + (size_t)n * (2 * 1156 * 16);
    for (int w = threadIdx.x; w < 528; w += 256) {
        int posi = w >> 2, rem = w & 3;
        int plane = rem >> 1, piece = rem & 1;
        int r, s;
        if (posi < 68) { r = (posi < 34) ? 0 : 33; s = posi % 34; }
        else { int e = posi - 68; r = 1 + (e >> 1); s = (e & 1) ? 33 : 0; }
        *(f16x8*)(base + ((size_t)plane * 1156 + r * 34 + s) * 16 + piece * 8) =
            (f16x8){0, 0, 0, 0, 0, 0, 0, 0};
    }
}

// ------- conv4 v4: LDS-staged planes, 2x2-site register blocking -------------
// Block = one image. 2 phases (ch-pair planes): stream plane (contiguous 37KB)
// into swizzled LDS, barrier, compute all window reads from LDS.
// Swizzle ss = site ^ ((site>>3)&7), plane stride 1164 (=4 mod 8):
// reads 2-way (free), staging writes 2-way (free) by bank-group arithmetic.
__global__ __launch_bounds__(256) void conv4_kernel4(
    const __half* __restrict__ Xp, const __half* __restrict__ Wh,
    const float* __restrict__ bias, float* __restrict__ out) {
    constexpr int PS = 1164;                  // plane stride in 16B slots
    __shared__ _Float16 lds[2 * PS * 8];      // 37,248 B
    int n = blockIdx.x;
    int t = threadIdx.x;
    int tx = t & 15, ty = t >> 4;
    int sa = ty * 2, sb = tx * 2;
    const __half* Xn = Xp + (size_t)n * (2 * 1156 * 16);
    float bv = bias[0];
    float accr[4][4];
    #pragma unroll
    for (int r = 0; r < 4; ++r)
        #pragma unroll
        for (int c = 0; c < 4; ++c) accr[r][c] = bv;

    #pragma unroll
    for (int p = 0; p < 2; ++p) {
        if (p) __syncthreads();               // phase-0 compute done before overwrite
        const __half* src = Xn + (size_t)p * (1156 * 16);
        for (int i = t; i < 2312; i += 256) {
            int site = i >> 1, piece = i & 1;
            int ss = site ^ ((site >> 3) & 7);
            *(f16x8*)(&lds[(piece * PS + ss) * 8]) = *(const f16x8*)(src + (size_t)i * 8);
        }
        __syncthreads();
        #pragma unroll
        for (int piece = 0; piece < 2; ++piece) {
            f16x8 win[4][4];
            #pragma unroll
            for (int u = 0; u < 4; ++u)
                #pragma unroll
                for (int v = 0; v < 4; ++v) {
                    int site = (sa + u) * 34 + sb + v;
                    int ss = site ^ ((site >> 3) & 7);
                    win[u][v] = *(const f16x8*)(&lds[(piece * PS + ss) * 8]);
                }
            const int cglob = p * 2 + piece;  // 8-channel chunk index 0..3
            #pragma unroll
            for (int dh = 0; dh < 4; ++dh) {
                #pragma unroll
                for (int dw = 0; dw < 4; ++dw) {
                    f16x8 w8 = *(const f16x8*)(Wh + (dh * 4 + dw) * 32 + cglob * 8);
                    const int pi = dh & 1, t1 = dh >> 1;
                    const int pj = dw & 1, t2 = dw >> 1;
                    #pragma unroll
                    for (int i2 = 0; i2 < 2; ++i2)
                        #pragma unroll
                        for (int j2 = 0; j2 < 2; ++j2) {
                            f16x8 x8 = win[i2 + pi + t1][j2 + pj + t2];
                            float a = accr[2 * i2 + pi][2 * j2 + pj];
                            #pragma unroll
                            for (int e = 0; e < 4; ++e)
                                a = dot2f((f16x2){x8[2 * e], x8[2 * e + 1]},
                                          (f16x2){w8[2 * e], w8[2 * e + 1]}, a);
                            accr[2 * i2 + pi][2 * j2 + pj] = a;
                        }
                }
            }
        }
    }
    #pragma unroll
    for (int r = 0; r < 4; ++r) {
        float4 v = {accr[r][0], accr[r][1], accr[r][2], accr[r][3]};
        *(float4*)(&out[((size_t)n * 64 + 2 * sa + r) * 64 + 2 * sb]) = v;
    }
}

// ---------------- launch -----------------------------------------------------
extern "C" void kernel_launch(void* const* d_in, const int* in_sizes, int n_in,
                              void* d_out, int out_size, void* d_ws, size_t ws_size,
                              hipStream_t stream) {
    const float* angles   = (const float*)d_in[0];
    const float* item_rep = (const float*)d_in[1];
    const float* W        = (const float*)d_in[2];
    const float* bfc      = (const float*)d_in[3];
    const float* k1       = (const float*)d_in[4];
    const float* b1       = (const float*)d_in[5];
    const float* k2       = (const float*)d_in[6];
    const float* b2       = (const float*)d_in[7];
    const float* k3       = (const float*)d_in[8];
    const float* b3       = (const float*)d_in[9];
    const float* k4       = (const float*)d_in[10];
    const float* b4       = (const float*)d_in[11];

    char* ws = (char*)d_ws;
    float*  Ctab  = (float*)(ws + 0);                 //  32 KB
    __half* itemh = (__half*)(ws + 32768);            //   2 MB
    __half* Bt1   = (__half*)(ws + 2129920);          //   1 MB
    __half* Bt2   = (__half*)(ws + 3178496);          // 256 KB
    __half* Bt3   = (__half*)(ws + 3440640);          //  64 KB
    __half* Kh4   = (__half*)(ws + 3506176);          //   1 KB
    __half* x0    = (__half*)(ws + 4194304);          //  16 MB -> 20,971,520
    __half* x1    = (__half*)(ws + 20971520);         //  32 MB -> 54,525,952
    __half* x3p   = (__half*)(ws + 4194304);          // 151.5 MB -> 155,713,536
    __half* Wtfc  = (__half*)(ws + 121634816);        //   4 MB (inside x3p, dead by conv3)
    __half* x2    = (__half*)(ws + 155713536);        //  64 MB -> 222,822,400
    float*  out   = (float*)d_out;

    coef_kernel<<<1, 512, 0, stream>>>(Ctab);
    wigner_kernel<<<NBATCH, 64, 0, stream>>>(angles, item_rep, Ctab, itemh);
    fcw_prep2<<<dim3(KPAD / 64, HID / 64), 256, 0, stream>>>(W, Wtfc);
    convw_prep<256, 128><<<16, 256, 0, stream>>>(k1, Bt1);
    convw_prep<128, 64><<<16, 256, 0, stream>>>(k2, Bt2);
    convw_prep<64, 32><<<16, 256, 0, stream>>>(k3, Bt3);
    conv4w_prep<<<2, 256, 0, stream>>>(k4, Kh4);

    // FC: 2048x512 @ 512x4096 -> x0
    fc_mfma<<<dim3(16, 32), 256, 0, stream>>>(itemh, Wtfc, bfc, x0);
    // conv1: 4x4x256 -> 8x8x128  (R=1, CF=4, y=2 slices, k-split B stages)
    convt_lds3<256, 128, 4, 1, 2, 4, 4, 2, 8, 0, 0><<<dim3(512, 2), 256, 0, stream>>>(x0, Bt1, b1, x1);
    // conv2: 8x8x128 -> 16x16x64 (R=2, CF=4) LDS = 32+32 = 64KB
    convt_lds3<128, 64, 8, 2, 3, 4, 4, 1, 16, 0, 0><<<dim3(1024, 1), 256, 0, stream>>>(x1, Bt2, b2, x2);
    // zero x3p border ring (plane-split layout), then conv3 writes the interior
    pad_zero2<<<NBATCH, 256, 0, stream>>>(x3p);
    // conv3: 16x16x64 -> plane-split (34x34 padded)x32 (R=4, CF=2) LDS = 40KB
    convt_lds3<64, 32, 16, 4, 4, 2, 4, 1, 34, 1, 1><<<dim3(2048, 1), 256, 0, stream>>>(x2, Bt3, b3, x3p);
    // conv4 v4: LDS-staged plane-split 34x34x32 -> 64x64x1 (fp32 out)
    conv4_kernel4<<<NBATCH, 256, 0, stream>>>(x3p, Kh4, b4, out);
}

// Round 11
// 320.019 us; speedup vs baseline: 1.1108x; 1.0606x over previous
//
#include <hip/hip_runtime.h>
#include <hip/hip_fp16.h>

#define DEG 6
#define RC 10
#define NBATCH 2048
#define FDIM 490
#define KPAD 512
#define HID 4096

typedef _Float16 f16x8 __attribute__((ext_vector_type(8)));
typedef _Float16 f16x2 __attribute__((ext_vector_type(2)));
typedef float f32x4 __attribute__((ext_vector_type(4)));

__device__ inline float dot2f(f16x2 x, f16x2 w, float acc) {
#if __has_builtin(__builtin_amdgcn_fdot2)
    return __builtin_amdgcn_fdot2(x, w, acc, false);
#else
    return acc + (float)x[0] * (float)w[0] + (float)x[1] * (float)w[1];
#endif
}

// ---------------- Wigner coefficient tables (device, each call) --------------
__global__ void coef_kernel(float* __restrict__ Ctab) {
    int p = blockIdx.x * blockDim.x + threadIdx.x;
    if (p >= 455) return;
    const int poff[8] = {0, 1, 10, 35, 84, 165, 286, 455};
    const int loff[7] = {0, 1, 28, 153, 496, 1225, 2556};
    int l = 0;
    while (p >= poff[l + 1]) ++l;
    int idx = p - poff[l];
    int nn = 2 * l + 1;
    int mpi = idx / nn, mi = idx % nn;
    int mp = mpi - l, m = mi - l;
    double f[13];
    f[0] = 1.0;
    for (int i = 1; i < 13; ++i) f[i] = f[i - 1] * i;
    double pref = sqrt(f[l + mp] * f[l - mp] * f[l + m] * f[l - m]);
    float* row = Ctab + loff[l] + (size_t)(mpi * nn + mi) * nn;
    for (int q = 0; q < nn; ++q) row[q] = 0.f;
    int s0 = max(0, m - mp), s1 = min(l + m, l - mp);
    for (int s = s0; s <= s1; ++s) {
        int q = mp - m + 2 * s;
        double den = f[l + m - s] * f[s] * f[mp - m + s] * f[l - mp - s];
        double t = pref / den;
        if ((mp - m + s) & 1) t = -t;
        row[q] += (float)t;
    }
}

// ---------------- Wigner D + item projection -> fp16 item[n][512] ------------
__global__ __launch_bounds__(64) void wigner_kernel(
    const float* __restrict__ angles, const float* __restrict__ item_rep,
    const float* __restrict__ Ctab, __half* __restrict__ item_h) {
    int n = blockIdx.x, lane = threadIdx.x;
    float alpha = angles[n * 3 + 0], beta = angles[n * 3 + 1], gamma = angles[n * 3 + 2];
    float cb = cosf(beta * 0.5f), sb = sinf(beta * 0.5f);
    __shared__ float dsh[169], Dsh[169], Psh[13];
    __shared__ float ear[13], eai[13], egr[13], egi[13];
    const int loff[7] = {0, 1, 28, 153, 496, 1225, 2556};
    const float isq = 0.7071067811865476f;
    for (int l = 0; l <= DEG; ++l) {
        int nn = 2 * l + 1;
        if (lane < nn) {
            int q = lane;
            float pv = 1.f;
            for (int i = 0; i < 2 * l - q; ++i) pv *= cb;
            for (int i = 0; i < q; ++i) pv *= sb;
            Psh[q] = pv;
            float mm = (float)(lane - l);
            float sa, ca; sincosf(alpha * mm, &sa, &ca);
            ear[lane] = ca; eai[lane] = -sa;
            float sg, cg; sincosf(gamma * mm, &sg, &cg);
            egr[lane] = cg; egi[lane] = -sg;
        }
        __syncthreads();
        const float* Cl = Ctab + loff[l];
        for (int e = lane; e < nn * nn; e += 64) {
            float acc = 0.f;
            const float* cr = Cl + e * nn;
            for (int q = 0; q < nn; ++q) acc += cr[q] * Psh[q];
            dsh[e] = acc;
        }
        __syncthreads();
        for (int e = lane; e < nn * nn; e += 64) {
            int u = e / nn, v = e - u * nn;
            int bn, bi0, bi1; float br0, br1, bm0, bm1;
            int mu = u - l;
            if (mu == 0)      { bn = 1; bi0 = l; br0 = 1.f; bm0 = 0.f; bi1 = 0; br1 = 0.f; bm1 = 0.f; }
            else if (mu > 0)  { bn = 2; bi0 = l + mu; br0 = (mu & 1) ? -isq : isq; bm0 = 0.f;
                                bi1 = l - mu; br1 = isq; bm1 = 0.f; }
            else              { int mm2 = -mu; bn = 2; bi0 = l - mm2; br0 = 0.f; bm0 = isq;
                                bi1 = l + mm2; br1 = 0.f; bm1 = (mm2 & 1) ? isq : -isq; }
            int cn, ci0, ci1; float cr0, cr1, cm0, cm1;
            int nu = v - l;
            if (nu == 0)      { cn = 1; ci0 = l; cr0 = 1.f; cm0 = 0.f; ci1 = 0; cr1 = 0.f; cm1 = 0.f; }
            else if (nu > 0)  { cn = 2; ci0 = l + nu; cr0 = (nu & 1) ? -isq : isq; cm0 = 0.f;
                                ci1 = l - nu; cr1 = isq; cm1 = 0.f; }
            else              { int mm2 = -nu; cn = 2; ci0 = l - mm2; cr0 = 0.f; cm0 = -isq;
                                ci1 = l + mm2; cr1 = 0.f; cm1 = (mm2 & 1) ? -isq : isq; }
            float acc = 0.f;
            #pragma unroll
            for (int pb = 0; pb < 2; ++pb) {
                if (pb >= bn) break;
                int b = pb ? bi1 : bi0;
                float sr = pb ? br1 : br0, si = pb ? bm1 : bm0;
                float z1r = sr * ear[b] - si * eai[b];
                float z1i = sr * eai[b] + si * ear[b];
                #pragma unroll
                for (int pc = 0; pc < 2; ++pc) {
                    if (pc >= cn) break;
                    int c = pc ? ci1 : ci0;
                    float tr = pc ? cr1 : cr0, ti = pc ? cm1 : cm0;
                    float dv = dsh[b * nn + c];
                    float z2r = egr[c] * tr - egi[c] * ti;
                    float z2i = egr[c] * ti + egi[c] * tr;
                    acc += dv * (z1r * z2r - z1i * z2i);
                }
            }
            Dsh[e] = acc;
        }
        __syncthreads();
        for (int e = lane; e < nn * RC; e += 64) {
            int u = e / RC, r = e - u * RC;
            float acc = 0.f;
            for (int v = 0; v < nn; ++v)
                acc += Dsh[u * nn + v] * item_rep[(l * l + v) * RC + r];
            item_h[(size_t)n * KPAD + (l * l + u) * RC + r] = __float2half(acc);
        }
        __syncthreads();
    }
    if (lane < KPAD - FDIM)
        item_h[(size_t)n * KPAD + FDIM + lane] = __float2half(0.f);
}

// ------- FC weight prep (tiled transpose): W[490,4096] f32 -> Wt[4096][512] f16
__global__ __launch_bounds__(256) void fcw_prep2(const float* __restrict__ W,
                                                 __half* __restrict__ Wt) {
    __shared__ _Float16 tile[64][72];
    int k0 = blockIdx.x * 64;
    int o0 = blockIdx.y * 64;
    int tid = threadIdx.x;
    int tx = tid & 63, ty = tid >> 6;
    #pragma unroll
    for (int i = 0; i < 16; ++i) {
        int k = k0 + ty + i * 4;
        float v = (k < FDIM) ? W[(size_t)k * HID + o0 + tx] : 0.f;
        tile[ty + i * 4][tx] = (_Float16)v;
    }
    __syncthreads();
    #pragma unroll
    for (int p = 0; p < 2; ++p) {
        int idx = tid + p * 256;
        int ol = idx >> 3;
        int kl = (idx & 7) * 8;
        f16x8 v;
        #pragma unroll
        for (int e = 0; e < 8; ++e) v[e] = tile[kl + e][ol];
        *(f16x8*)(Wt + (size_t)(o0 + ol) * KPAD + k0 + kl) = v;
    }
}

// ---- conv weight prep: K[4][4][CIN][COUT] f32 -> Bt[par][COUT][4*CIN] f16 ---
template <int CIN, int COUT>
__global__ __launch_bounds__(256) void convw_prep(const float* __restrict__ K,
                                                  __half* __restrict__ Bt) {
    int par = blockIdx.x >> 2, tap = blockIdx.x & 3;
    int pi = par & 1, pj = par >> 1;
    int t1 = tap >> 1, t2 = tap & 1;
    int dh = pi + 2 * t1, dw = pj + 2 * t2;
    const float* Ks = K + (size_t)(dh * 4 + dw) * CIN * COUT;
    int o = threadIdx.x % COUT;
    int cg = threadIdx.x / COUT;
    constexpr int NG = 256 / COUT;
    for (int c0 = cg * 8; c0 < CIN; c0 += NG * 8) {
        f16x8 v;
        #pragma unroll
        for (int e = 0; e < 8; ++e) v[e] = (_Float16)Ks[(size_t)(c0 + e) * COUT + o];
        *(f16x8*)(Bt + ((size_t)par * COUT + o) * (4 * CIN) + tap * CIN + c0) = v;
    }
}

// ---- conv4 weight prep: K[4][4][32][1] f32 -> f16 [16][32] ------------------
__global__ __launch_bounds__(256) void conv4w_prep(const float* __restrict__ K,
                                                   __half* __restrict__ Kh) {
    int t = blockIdx.x * blockDim.x + threadIdx.x;
    if (t < 512) Kh[t] = __float2half(K[t]);
}

// ---------------- FC as MFMA GEMM: [2048x512] x [512x4096] + relu -> f16 -----
__global__ __launch_bounds__(256) void fc_mfma(
    const __half* __restrict__ A, const __half* __restrict__ Wt,
    const float* __restrict__ bias, __half* __restrict__ Y) {
    int lane = threadIdx.x & 63, wid = threadIdx.x >> 6;
    int job = blockIdx.x * 4 + wid;
    int mbase = job * 32;
    int cb = blockIdx.y * 128;
    int klane = (lane >> 4) * 8, coll = lane & 15;
    const __half* pA0 = A + (size_t)(mbase + coll) * KPAD + klane;
    const __half* pB0 = Wt + (size_t)(cb + coll) * KPAD + klane;
    f32x4 acc[2][8] = {};
    for (int s = 0; s < 16; ++s) {
        f16x8 a0 = *(const f16x8*)(pA0 + s * 32);
        f16x8 a1 = *(const f16x8*)(pA0 + 16 * KPAD + s * 32);
        #pragma unroll
        for (int f = 0; f < 8; ++f) {
            f16x8 b = *(const f16x8*)(pB0 + (size_t)f * 16 * KPAD + s * 32);
            acc[0][f] = __builtin_amdgcn_mfma_f32_16x16x32_f16(a0, b, acc[0][f], 0, 0, 0);
            acc[1][f] = __builtin_amdgcn_mfma_f32_16x16x32_f16(a1, b, acc[1][f], 0, 0, 0);
        }
    }
    #pragma unroll
    for (int f = 0; f < 8; ++f) {
        float bv = bias[cb + f * 16 + coll];
        #pragma unroll
        for (int r = 0; r < 2; ++r)
            #pragma unroll
            for (int g = 0; g < 4; ++g) {
                int m = mbase + r * 16 + (lane >> 4) * 4 + g;
                float v = acc[r][f][g] + bv;
                v = v > 0.f ? v : 0.f;
                Y[(size_t)m * HID + cb + f * 16 + coll] = __float2half(v);
            }
    }
}

// ------- conv_transpose: A + double-buffered B both in LDS, serial parity ----
template <int CIN, int COUT, int HIN, int R, int LOGH, int CF, int WAVES, int KSPLIT, int OH, int OB>
__global__ __launch_bounds__(WAVES * 64) void convt_lds3(
    const __half* __restrict__ X, const __half* __restrict__ Bt,
    const float* __restrict__ bias, __half* __restrict__ Y) {
    constexpr int HH = HIN * HIN;
    constexpr int KTOT = 4 * CIN;
    constexpr int CINS = CIN / KSPLIT;
    constexpr int NSTEPS = CINS / 32;
    constexpr int SL = CIN / 8;
    constexpr int SLB = CINS / 8;
    constexpr int T = WAVES * 64;
    constexpr int POS = WAVES * R * 16;
    constexpr int AROWS = POS;
    constexpr int AH = AROWS * CIN;
    constexpr int BROWS = CF * 16;
    constexpr int BH = BROWS * CINS;
    constexpr int SA = AROWS * SL;
    constexpr int SB = BROWS * SLB;
    constexpr int NSB = SB / T;
    constexpr int NST = 16 * KSPLIT;
    __shared__ _Float16 lds[AH + 2 * BH];

    int tid = threadIdx.x;
    int lane = tid & 63, w = tid >> 6;
    int kg = lane >> 4, coll = lane & 15;
    int n0 = blockIdx.x * (POS >> (2 * LOGH));
    int cbase = blockIdx.y * (CF * 16);
    int posbase = w * (R * 16);

    const __half* Xs = X + (size_t)n0 * HH * CIN;
    #pragma unroll
    for (int q = 0; q < SA / T; ++q) {
        int i = tid + q * T;
        int row = i / SL, slot = i % SL;
        f16x8 v = *(const f16x8*)(Xs + (size_t)i * 8);
        *(f16x8*)(&lds[row * CIN + ((slot ^ (row & 7)) * 8)]) = v;
    }
    f16x8 breg[NSB];
    #pragma unroll
    for (int q = 0; q < NSB; ++q) {
        int i = tid + q * T;
        int o = i / SLB, sl = i % SLB;
        breg[q] = *(const f16x8*)(Bt + ((size_t)(cbase + o) * KTOT) + sl * 8);
    }
    #pragma unroll
    for (int q = 0; q < NSB; ++q) {
        int i = tid + q * T;
        int o = i / SLB, sl = i % SLB;
        *(f16x8*)(&lds[AH + o * CINS + ((sl ^ (o & 7)) * 8)]) = breg[q];
    }
    __syncthreads();

    int posl[R]; bool okr[R][3], okc[R][3];
    #pragma unroll
    for (int r = 0; r < R; ++r) {
        int p = posbase + r * 16 + coll;
        posl[r] = p;
        int rem = p & (HH - 1);
        int a = rem >> LOGH, b = rem & (HIN - 1);
        #pragma unroll
        for (int s = 0; s < 3; ++s) {
            okr[r][s] = (unsigned)(a + s - 1) < (unsigned)HIN;
            okc[r][s] = (unsigned)(b + s - 1) < (unsigned)HIN;
        }
    }

    float bvv[CF];
    #pragma unroll
    for (int f = 0; f < CF; ++f) bvv[f] = bias[cbase + f * 16 + coll];

    #pragma unroll
    for (int par = 0; par < 4; ++par) {
        const int pi = par & 1, pj = par >> 1;
        f32x4 acc[R][CF];
        #pragma unroll
        for (int r = 0; r < R; ++r)
            #pragma unroll
            for (int f = 0; f < CF; ++f)
                acc[r][f] = (f32x4){bvv[f], bvv[f], bvv[f], bvv[f]};

        #pragma unroll
        for (int tt = 0; tt < 4 * KSPLIT; ++tt) {
            const int s = par * 4 * KSPLIT + tt;
            const int tap = tt / KSPLIT;
            const int kh = tt % KSPLIT;
            const int buf = s & 1;
            if (s + 1 < NST) {
                const int s2 = s + 1;
                const int par2 = s2 / (4 * KSPLIT);
                const int tt2 = s2 % (4 * KSPLIT);
                const int tap2 = tt2 / KSPLIT;
                const int kh2 = tt2 % KSPLIT;
                #pragma unroll
                for (int q = 0; q < NSB; ++q) {
                    int i = tid + q * T;
                    int o = i / SLB, sl = i % SLB;
                    breg[q] = *(const f16x8*)(Bt +
                        ((size_t)(par2 * COUT + cbase + o) * KTOT +
                         tap2 * CIN + kh2 * CINS) + sl * 8);
                }
            }
            const int iu = (tap >> 1) + pi, iv = (tap & 1) + pj;
            const int delta = (iu - 1) * HIN + (iv - 1);
            int rp[R]; bool ok[R];
            #pragma unroll
            for (int r = 0; r < R; ++r) {
                int t = posl[r] + delta;
                rp[r] = min(max(t, 0), AROWS - 1);
                ok[r] = okr[r][iu] && okc[r][iv];
            }
            const _Float16* Bl = &lds[AH + buf * BH];
            #pragma unroll
            for (int cc = 0; cc < NSTEPS; ++cc) {
                const int slB = cc * 4 + kg;
                const int slA = kh * SLB + slB;
                f16x8 b[CF];
                #pragma unroll
                for (int f = 0; f < CF; ++f)
                    b[f] = *(const f16x8*)(&Bl[(f * 16 + coll) * CINS +
                                               ((slB ^ (coll & 7)) * 8)]);
                f16x8 a[R];
                #pragma unroll
                for (int r = 0; r < R; ++r) {
                    f16x8 v = *(const f16x8*)(&lds[rp[r] * CIN +
                                                   ((slA ^ (rp[r] & 7)) * 8)]);
                    a[r] = ok[r] ? v : (f16x8){0, 0, 0, 0, 0, 0, 0, 0};
                }
                #pragma unroll
                for (int r = 0; r < R; ++r)
                    #pragma unroll
                    for (int f = 0; f < CF; ++f)
                        acc[r][f] = __builtin_amdgcn_mfma_f32_16x16x32_f16(
                            a[r], b[f], acc[r][f], 0, 0, 0);
            }
            if (s + 1 < NST) {
                #pragma unroll
                for (int q = 0; q < NSB; ++q) {
                    int i = tid + q * T;
                    int o = i / SLB, sl = i % SLB;
                    *(f16x8*)(&lds[AH + ((s + 1) & 1) * BH + o * CINS +
                                   ((sl ^ (o & 7)) * 8)]) = breg[q];
                }
                __syncthreads();
            }
        }

        #pragma unroll
        for (int r = 0; r < R; ++r) {
            #pragma unroll
            for (int g = 0; g < 4; ++g) {
                int p = posbase + r * 16 + kg * 4 + g;
                int ni = p >> (2 * LOGH);
                int rem = p & (HH - 1);
                int a2 = rem >> LOGH, b2 = rem & (HIN - 1);
                size_t ob = (((size_t)(n0 + ni) * OH + 2 * a2 + pi + OB) * OH +
                             2 * b2 + pj + OB) * COUT;
                #pragma unroll
                for (int f = 0; f < CF; ++f) {
                    float v = acc[r][f][g];
                    v = v > 0.f ? v : 0.f;
                    Y[ob + cbase + f * 16 + coll] = __float2half(v);
                }
            }
        }
    }
}

// ------- conv3+conv4 FUSED: block = one image; conv3 output never leaves LDS -
// conv3 part: CIN=64, COUT=32, HIN=16, R=4, 4 waves, full acc[4par][4r][2cf].
// Then per 16-ch piece: relu'd acc -> swizzled LDS plane [2][1164][8ch]
// (reusing dead A/B region), barrier, conv4 2x2-site window compute (proven
// conv4_kernel4 code), barrier. Final: 64x64 fp32 coalesced float4 stores.
__global__ __launch_bounds__(256) void conv34_fused(
    const __half* __restrict__ X, const __half* __restrict__ Bt,
    const float* __restrict__ bias3, const __half* __restrict__ Wh4,
    const float* __restrict__ bias4, float* __restrict__ out) {
    constexpr int CIN = 64, HIN = 16, HH = 256, KTOT = 256;
    constexpr int SL = 8, T = 256, AROWS = 256, AH = AROWS * CIN;  // 16384 halves
    constexpr int BH = 32 * CIN;                                   // 2048 halves
    constexpr int PS = 1164;  // plane sub-stride (16B slots) for conv4 phase
    __shared__ _Float16 lds[AH + 2 * BH];   // 40,960 B; plane (37,248 B) aliases it

    int tid = threadIdx.x;
    int lane = tid & 63, w = tid >> 6;
    int kg = lane >> 4, coll = lane & 15;
    int n = blockIdx.x;
    int posbase = w * 64;

    // ---- stage A (whole 16x16x64 image) ----
    const __half* Xs = X + (size_t)n * HH * CIN;
    #pragma unroll
    for (int q = 0; q < 8; ++q) {
        int i = tid + q * T;
        int row = i / SL, slot = i % SL;
        f16x8 v = *(const f16x8*)(Xs + (size_t)i * 8);
        *(f16x8*)(&lds[row * CIN + ((slot ^ (row & 7)) * 8)]) = v;
    }
    // ---- stage B for stage 0 ----
    {
        int o = tid / SL, sl = tid % SL;
        f16x8 b0 = *(const f16x8*)(Bt + (size_t)o * KTOT + sl * 8);
        *(f16x8*)(&lds[AH + o * CIN + ((sl ^ (o & 7)) * 8)]) = b0;
    }
    __syncthreads();

    int posl[4]; bool okr[4][3], okc[4][3];
    #pragma unroll
    for (int r = 0; r < 4; ++r) {
        int p = posbase + r * 16 + coll;
        posl[r] = p;
        int a = p >> 4, b = p & 15;
        #pragma unroll
        for (int s = 0; s < 3; ++s) {
            okr[r][s] = (unsigned)(a + s - 1) < (unsigned)HIN;
            okc[r][s] = (unsigned)(b + s - 1) < (unsigned)HIN;
        }
    }

    float bv0 = bias3[coll], bv1 = bias3[16 + coll];
    f32x4 acc[4][4][2];
    #pragma unroll
    for (int par = 0; par < 4; ++par)
        #pragma unroll
        for (int r = 0; r < 4; ++r) {
            acc[par][r][0] = (f32x4){bv0, bv0, bv0, bv0};
            acc[par][r][1] = (f32x4){bv1, bv1, bv1, bv1};
        }

    f16x8 breg;
    #pragma unroll
    for (int s = 0; s < 16; ++s) {
        const int par = s >> 2, tap = s & 3;
        const int pi = par & 1, pj = par >> 1;
        const int buf = s & 1;
        if (s + 1 < 16) {
            const int par2 = (s + 1) >> 2, tap2 = (s + 1) & 3;
            int o = tid / SL, sl = tid % SL;
            breg = *(const f16x8*)(Bt + ((size_t)(par2 * 32 + o) * KTOT +
                                         tap2 * CIN) + sl * 8);
        }
        const int iu = (tap >> 1) + pi, iv = (tap & 1) + pj;
        const int delta = (iu - 1) * HIN + (iv - 1);
        int rp[4]; bool ok[4];
        #pragma unroll
        for (int r = 0; r < 4; ++r) {
            int t2 = posl[r] + delta;
            rp[r] = min(max(t2, 0), AROWS - 1);
            ok[r] = okr[r][iu] && okc[r][iv];
        }
        const _Float16* Bl = &lds[AH + buf * BH];
        #pragma unroll
        for (int cc = 0; cc < 2; ++cc) {
            const int sl2 = cc * 4 + kg;
            f16x8 b[2];
            #pragma unroll
            for (int f = 0; f < 2; ++f)
                b[f] = *(const f16x8*)(&Bl[(f * 16 + coll) * CIN +
                                           ((sl2 ^ (coll & 7)) * 8)]);
            f16x8 a[4];
            #pragma unroll
            for (int r = 0; r < 4; ++r) {
                f16x8 v = *(const f16x8*)(&lds[rp[r] * CIN +
                                               ((sl2 ^ (rp[r] & 7)) * 8)]);
                a[r] = ok[r] ? v : (f16x8){0, 0, 0, 0, 0, 0, 0, 0};
            }
            #pragma unroll
            for (int r = 0; r < 4; ++r)
                #pragma unroll
                for (int f = 0; f < 2; ++f)
                    acc[par][r][f] = __builtin_amdgcn_mfma_f32_16x16x32_f16(
                        a[r], b[f], acc[par][r][f], 0, 0, 0);
        }
        if (s + 1 < 16) {
            int o = tid / SL, sl = tid % SL;
            *(f16x8*)(&lds[AH + ((s + 1) & 1) * BH + o * CIN +
                           ((sl ^ (o & 7)) * 8)]) = breg;
            __syncthreads();
        }
    }
    __syncthreads();   // A/B regions now dead; plane buffer takes over

    // ---- conv4 phase ----
    int tx = tid & 15, ty = tid >> 4;
    int sa = ty * 2, sb = tx * 2;
    float bv4 = bias4[0];
    float accr[4][4];
    #pragma unroll
    for (int r = 0; r < 4; ++r)
        #pragma unroll
        for (int c = 0; c < 4; ++c) accr[r][c] = bv4;

    #pragma unroll
    for (int piece = 0; piece < 2; ++piece) {   // 16-ch half (= conv3 CF frag)
        // zero border ring (132 sites x 2 sub-pieces)
        for (int i = tid; i < 264; i += 256) {
            int posi = i >> 1, q = i & 1;
            int rr, sc;
            if (posi < 68) { rr = (posi < 34) ? 0 : 33; sc = posi % 34; }
            else { int e = posi - 68; rr = 1 + (e >> 1); sc = (e & 1) ? 33 : 0; }
            int site = rr * 34 + sc;
            int ss = site ^ ((site >> 3) & 7);
            *(f16x8*)(&lds[(q * PS + ss) * 8]) = (f16x8){0, 0, 0, 0, 0, 0, 0, 0};
        }
        // write relu'd conv3 output (this 16-ch piece) into the plane
        #pragma unroll
        for (int par = 0; par < 4; ++par) {
            const int pi = par & 1, pj = par >> 1;
            #pragma unroll
            for (int r = 0; r < 4; ++r) {
                #pragma unroll
                for (int g = 0; g < 4; ++g) {
                    int p = posbase + r * 16 + kg * 4 + g;
                    int a2 = p >> 4, b2 = p & 15;
                    int site = (2 * a2 + pi + 1) * 34 + (2 * b2 + pj + 1);
                    int ss = site ^ ((site >> 3) & 7);
                    float v = acc[par][r][piece][g];
                    v = v > 0.f ? v : 0.f;
                    lds[((coll >> 3) * PS + ss) * 8 + (coll & 7)] = (_Float16)v;
                }
            }
        }
        __syncthreads();
        // conv4 window compute for this 16-ch piece (2 sub-pieces of 8 ch)
        #pragma unroll
        for (int q = 0; q < 2; ++q) {
            f16x8 win[4][4];
            #pragma unroll
            for (int u = 0; u < 4; ++u)
                #pragma unroll
                for (int v = 0; v < 4; ++v) {
                    int site = (sa + u) * 34 + sb + v;
                    int ss = site ^ ((site >> 3) & 7);
                    win[u][v] = *(const f16x8*)(&lds[(q * PS + ss) * 8]);
                }
            const int cglob = piece * 2 + q;
            #pragma unroll
            for (int dh = 0; dh < 4; ++dh) {
                #pragma unroll
                for (int dw = 0; dw < 4; ++dw) {
                    f16x8 w8 = *(const f16x8*)(Wh4 + (dh * 4 + dw) * 32 + cglob * 8);
                    const int pi = dh & 1, t1 = dh >> 1;
                    const int pj = dw & 1, t2 = dw >> 1;
                    #pragma unroll
                    for (int i2 = 0; i2 < 2; ++i2)
                        #pragma unroll
                        for (int j2 = 0; j2 < 2; ++j2) {
                            f16x8 x8 = win[i2 + pi + t1][j2 + pj + t2];
                            float a = accr[2 * i2 + pi][2 * j2 + pj];
                            #pragma unroll
                            for (int e = 0; e < 4; ++e)
                                a = dot2f((f16x2){x8[2 * e], x8[2 * e + 1]},
                                          (f16x2){w8[2 * e], w8[2 * e + 1]}, a);
                            accr[2 * i2 + pi][2 * j2 + pj] = a;
                        }
                }
            }
        }
        __syncthreads();   // before next piece overwrites the plane
    }
    #pragma unroll
    for (int r = 0; r < 4; ++r) {
        float4 v = {accr[r][0], accr[r][1], accr[r][2], accr[r][3]};
        *(float4*)(&out[((size_t)n * 64 + 2 * sa + r) * 64 + 2 * sb]) = v;
    }
}

// ---------------- launch -----------------------------------------------------
extern "C" void kernel_launch(void* const* d_in, const int* in_sizes, int n_in,
                              void* d_out, int out_size, void* d_ws, size_t ws_size,
                              hipStream_t stream) {
    const float* angles   = (const float*)d_in[0];
    const float* item_rep = (const float*)d_in[1];
    const float* W        = (const float*)d_in[2];
    const float* bfc      = (const float*)d_in[3];
    const float* k1       = (const float*)d_in[4];
    const float* b1       = (const float*)d_in[5];
    const float* k2       = (const float*)d_in[6];
    const float* b2       = (const float*)d_in[7];
    const float* k3       = (const float*)d_in[8];
    const float* b3       = (const float*)d_in[9];
    const float* k4       = (const float*)d_in[10];
    const float* b4       = (const float*)d_in[11];

    char* ws = (char*)d_ws;
    float*  Ctab  = (float*)(ws + 0);                 //  32 KB
    __half* itemh = (__half*)(ws + 32768);            //   2 MB
    __half* Bt1   = (__half*)(ws + 2129920);          //   1 MB
    __half* Bt2   = (__half*)(ws + 3178496);          // 256 KB
    __half* Bt3   = (__half*)(ws + 3440640);          //  64 KB
    __half* Kh4   = (__half*)(ws + 3506176);          //   1 KB
    __half* x0    = (__half*)(ws + 4194304);          //  16 MB -> 20,971,520
    __half* x1    = (__half*)(ws + 20971520);         //  32 MB -> 54,525,952
    __half* Wtfc  = (__half*)(ws + 121634816);        //   4 MB (dead region reuse)
    __half* x2    = (__half*)(ws + 155713536);        //  64 MB -> 222,822,400
    float*  out   = (float*)d_out;

    coef_kernel<<<1, 512, 0, stream>>>(Ctab);
    wigner_kernel<<<NBATCH, 64, 0, stream>>>(angles, item_rep, Ctab, itemh);
    fcw_prep2<<<dim3(KPAD / 64, HID / 64), 256, 0, stream>>>(W, Wtfc);
    convw_prep<256, 128><<<16, 256, 0, stream>>>(k1, Bt1);
    convw_prep<128, 64><<<16, 256, 0, stream>>>(k2, Bt2);
    convw_prep<64, 32><<<16, 256, 0, stream>>>(k3, Bt3);
    conv4w_prep<<<2, 256, 0, stream>>>(k4, Kh4);

    // FC: 2048x512 @ 512x4096 -> x0
    fc_mfma<<<dim3(16, 32), 256, 0, stream>>>(itemh, Wtfc, bfc, x0);
    // conv1: 4x4x256 -> 8x8x128  (R=1, CF=4, y=2 slices, k-split B stages)
    convt_lds3<256, 128, 4, 1, 2, 4, 4, 2, 8, 0><<<dim3(512, 2), 256, 0, stream>>>(x0, Bt1, b1, x1);
    // conv2: 8x8x128 -> 16x16x64 (R=2, CF=4) LDS = 32+32 = 64KB
    convt_lds3<128, 64, 8, 2, 3, 4, 4, 1, 16, 0><<<dim3(1024, 1), 256, 0, stream>>>(x1, Bt2, b2, x2);
    // conv3+conv4 fused: 16x16x64 -> (LDS) -> 64x64x1 fp32
    conv34_fused<<<NBATCH, 256, 0, stream>>>(x2, Bt3, b3, Kh4, b4, out);
}

// Round 12
// 313.924 us; speedup vs baseline: 1.1324x; 1.0194x over previous
//
#include <hip/hip_runtime.h>
#include <hip/hip_fp16.h>

#define DEG 6
#define RC 10
#define NBATCH 2048
#define FDIM 490
#define KPAD 512
#define HID 4096

typedef _Float16 f16x8 __attribute__((ext_vector_type(8)));
typedef _Float16 f16x4 __attribute__((ext_vector_type(4)));
typedef _Float16 f16x2 __attribute__((ext_vector_type(2)));
typedef float f32x4 __attribute__((ext_vector_type(4)));

// ---------------- Wigner coefficient tables (device, each call) --------------
__global__ void coef_kernel(float* __restrict__ Ctab) {
    int p = blockIdx.x * blockDim.x + threadIdx.x;
    if (p >= 455) return;
    const int poff[8] = {0, 1, 10, 35, 84, 165, 286, 455};
    const int loff[7] = {0, 1, 28, 153, 496, 1225, 2556};
    int l = 0;
    while (p >= poff[l + 1]) ++l;
    int idx = p - poff[l];
    int nn = 2 * l + 1;
    int mpi = idx / nn, mi = idx % nn;
    int mp = mpi - l, m = mi - l;
    double f[13];
    f[0] = 1.0;
    for (int i = 1; i < 13; ++i) f[i] = f[i - 1] * i;
    double pref = sqrt(f[l + mp] * f[l - mp] * f[l + m] * f[l - m]);
    float* row = Ctab + loff[l] + (size_t)(mpi * nn + mi) * nn;
    for (int q = 0; q < nn; ++q) row[q] = 0.f;
    int s0 = max(0, m - mp), s1 = min(l + m, l - mp);
    for (int s = s0; s <= s1; ++s) {
        int q = mp - m + 2 * s;
        double den = f[l + m - s] * f[s] * f[mp - m + s] * f[l - mp - s];
        double t = pref / den;
        if ((mp - m + s) & 1) t = -t;
        row[q] += (float)t;
    }
}

// ---------------- Wigner D + item projection -> fp16 item[n][512] ------------
__global__ __launch_bounds__(64) void wigner_kernel(
    const float* __restrict__ angles, const float* __restrict__ item_rep,
    const float* __restrict__ Ctab, __half* __restrict__ item_h) {
    int n = blockIdx.x, lane = threadIdx.x;
    float alpha = angles[n * 3 + 0], beta = angles[n * 3 + 1], gamma = angles[n * 3 + 2];
    float cb = cosf(beta * 0.5f), sb = sinf(beta * 0.5f);
    __shared__ float dsh[169], Dsh[169], Psh[13];
    __shared__ float ear[13], eai[13], egr[13], egi[13];
    const int loff[7] = {0, 1, 28, 153, 496, 1225, 2556};
    const float isq = 0.7071067811865476f;
    for (int l = 0; l <= DEG; ++l) {
        int nn = 2 * l + 1;
        if (lane < nn) {
            int q = lane;
            float pv = 1.f;
            for (int i = 0; i < 2 * l - q; ++i) pv *= cb;
            for (int i = 0; i < q; ++i) pv *= sb;
            Psh[q] = pv;
            float mm = (float)(lane - l);
            float sa, ca; sincosf(alpha * mm, &sa, &ca);
            ear[lane] = ca; eai[lane] = -sa;
            float sg, cg; sincosf(gamma * mm, &sg, &cg);
            egr[lane] = cg; egi[lane] = -sg;
        }
        __syncthreads();
        const float* Cl = Ctab + loff[l];
        for (int e = lane; e < nn * nn; e += 64) {
            float acc = 0.f;
            const float* cr = Cl + e * nn;
            for (int q = 0; q < nn; ++q) acc += cr[q] * Psh[q];
            dsh[e] = acc;
        }
        __syncthreads();
        for (int e = lane; e < nn * nn; e += 64) {
            int u = e / nn, v = e - u * nn;
            int bn, bi0, bi1; float br0, br1, bm0, bm1;
            int mu = u - l;
            if (mu == 0)      { bn = 1; bi0 = l; br0 = 1.f; bm0 = 0.f; bi1 = 0; br1 = 0.f; bm1 = 0.f; }
            else if (mu > 0)  { bn = 2; bi0 = l + mu; br0 = (mu & 1) ? -isq : isq; bm0 = 0.f;
                                bi1 = l - mu; br1 = isq; bm1 = 0.f; }
            else              { int mm2 = -mu; bn = 2; bi0 = l - mm2; br0 = 0.f; bm0 = isq;
                                bi1 = l + mm2; br1 = 0.f; bm1 = (mm2 & 1) ? isq : -isq; }
            int cn, ci0, ci1; float cr0, cr1, cm0, cm1;
            int nu = v - l;
            if (nu == 0)      { cn = 1; ci0 = l; cr0 = 1.f; cm0 = 0.f; ci1 = 0; cr1 = 0.f; cm1 = 0.f; }
            else if (nu > 0)  { cn = 2; ci0 = l + nu; cr0 = (nu & 1) ? -isq : isq; cm0 = 0.f;
                                ci1 = l - nu; cr1 = isq; cm1 = 0.f; }
            else              { int mm2 = -nu; cn = 2; ci0 = l - mm2; cr0 = 0.f; cm0 = -isq;
                                ci1 = l + mm2; cr1 = 0.f; cm1 = (mm2 & 1) ? -isq : isq; }
            float acc = 0.f;
            #pragma unroll
            for (int pb = 0; pb < 2; ++pb) {
                if (pb >= bn) break;
                int b = pb ? bi1 : bi0;
                float sr = pb ? br1 : br0, si = pb ? bm1 : bm0;
                float z1r = sr * ear[b] - si * eai[b];
                float z1i = sr * eai[b] + si * ear[b];
                #pragma unroll
                for (int pc = 0; pc < 2; ++pc) {
                    if (pc >= cn) break;
                    int c = pc ? ci1 : ci0;
                    float tr = pc ? cr1 : cr0, ti = pc ? cm1 : cm0;
                    float dv = dsh[b * nn + c];
                    float z2r = egr[c] * tr - egi[c] * ti;
                    float z2i = egr[c] * ti + egi[c] * tr;
                    acc += dv * (z1r * z2r - z1i * z2i);
                }
            }
            Dsh[e] = acc;
        }
        __syncthreads();
        for (int e = lane; e < nn * RC; e += 64) {
            int u = e / RC, r = e - u * RC;
            float acc = 0.f;
            for (int v = 0; v < nn; ++v)
                acc += Dsh[u * nn + v] * item_rep[(l * l + v) * RC + r];
            item_h[(size_t)n * KPAD + (l * l + u) * RC + r] = __float2half(acc);
        }
        __syncthreads();
    }
    if (lane < KPAD - FDIM)
        item_h[(size_t)n * KPAD + FDIM + lane] = __float2half(0.f);
}

// ------- FC weight prep (tiled transpose): W[490,4096] f32 -> Wt[4096][512] f16
__global__ __launch_bounds__(256) void fcw_prep2(const float* __restrict__ W,
                                                 __half* __restrict__ Wt) {
    __shared__ _Float16 tile[64][72];
    int k0 = blockIdx.x * 64;
    int o0 = blockIdx.y * 64;
    int tid = threadIdx.x;
    int tx = tid & 63, ty = tid >> 6;
    #pragma unroll
    for (int i = 0; i < 16; ++i) {
        int k = k0 + ty + i * 4;
        float v = (k < FDIM) ? W[(size_t)k * HID + o0 + tx] : 0.f;
        tile[ty + i * 4][tx] = (_Float16)v;
    }
    __syncthreads();
    #pragma unroll
    for (int p = 0; p < 2; ++p) {
        int idx = tid + p * 256;
        int ol = idx >> 3;
        int kl = (idx & 7) * 8;
        f16x8 v;
        #pragma unroll
        for (int e = 0; e < 8; ++e) v[e] = tile[kl + e][ol];
        *(f16x8*)(Wt + (size_t)(o0 + ol) * KPAD + k0 + kl) = v;
    }
}

// ---- conv weight prep: K[4][4][CIN][COUT] f32 -> Bt[par][COUT][4*CIN] f16 ---
template <int CIN, int COUT>
__global__ __launch_bounds__(256) void convw_prep(const float* __restrict__ K,
                                                  __half* __restrict__ Bt) {
    int par = blockIdx.x >> 2, tap = blockIdx.x & 3;
    int pi = par & 1, pj = par >> 1;
    int t1 = tap >> 1, t2 = tap & 1;
    int dh = pi + 2 * t1, dw = pj + 2 * t2;
    const float* Ks = K + (size_t)(dh * 4 + dw) * CIN * COUT;
    int o = threadIdx.x % COUT;
    int cg = threadIdx.x / COUT;
    constexpr int NG = 256 / COUT;
    for (int c0 = cg * 8; c0 < CIN; c0 += NG * 8) {
        f16x8 v;
        #pragma unroll
        for (int e = 0; e < 8; ++e) v[e] = (_Float16)Ks[(size_t)(c0 + e) * COUT + o];
        *(f16x8*)(Bt + ((size_t)par * COUT + o) * (4 * CIN) + tap * CIN + c0) = v;
    }
}

// ---- conv4 merged-shift weight table: W4m[piece(2)][sp(5)][row16][k32] f16 --
// row = parity (rows 4..15 zero); k = h*16 + ch: shift s = sp*2+h (s in 0..8,
// s==9 pad -> 0), (iu,iv) = (s/3, s%3); valid iff t1=iu-pi, t2=iv-pj in {0,1}.
__global__ __launch_bounds__(256) void w4m_prep(const float* __restrict__ K4,
                                                __half* __restrict__ W4m) {
    int t = blockIdx.x * 256 + threadIdx.x;
    if (t >= 5120) return;
    int piece = t / 2560;
    int rem = t - piece * 2560;
    int sp = rem / 512;
    int rem2 = rem - sp * 512;
    int row = rem2 >> 5;
    int k = rem2 & 31;
    int h = k >> 4, c = k & 15;
    int s = sp * 2 + h;
    float v = 0.f;
    if (row < 4 && s < 9) {
        int iu = s / 3, iv = s % 3;
        int pi = row & 1, pj = row >> 1;
        int t1 = iu - pi, t2 = iv - pj;
        if (((unsigned)t1 < 2u) && ((unsigned)t2 < 2u)) {
            int dh = pi + 2 * t1, dw = pj + 2 * t2;
            v = K4[(dh * 4 + dw) * 32 + piece * 16 + c];
        }
    }
    W4m[t] = __float2half(v);
}

// ---------------- FC as MFMA GEMM: [2048x512] x [512x4096] + relu -> f16 -----
__global__ __launch_bounds__(256) void fc_mfma(
    const __half* __restrict__ A, const __half* __restrict__ Wt,
    const float* __restrict__ bias, __half* __restrict__ Y) {
    int lane = threadIdx.x & 63, wid = threadIdx.x >> 6;
    int job = blockIdx.x * 4 + wid;
    int mbase = job * 32;
    int cb = blockIdx.y * 128;
    int klane = (lane >> 4) * 8, coll = lane & 15;
    const __half* pA0 = A + (size_t)(mbase + coll) * KPAD + klane;
    const __half* pB0 = Wt + (size_t)(cb + coll) * KPAD + klane;
    f32x4 acc[2][8] = {};
    for (int s = 0; s < 16; ++s) {
        f16x8 a0 = *(const f16x8*)(pA0 + s * 32);
        f16x8 a1 = *(const f16x8*)(pA0 + 16 * KPAD + s * 32);
        #pragma unroll
        for (int f = 0; f < 8; ++f) {
            f16x8 b = *(const f16x8*)(pB0 + (size_t)f * 16 * KPAD + s * 32);
            acc[0][f] = __builtin_amdgcn_mfma_f32_16x16x32_f16(a0, b, acc[0][f], 0, 0, 0);
            acc[1][f] = __builtin_amdgcn_mfma_f32_16x16x32_f16(a1, b, acc[1][f], 0, 0, 0);
        }
    }
    #pragma unroll
    for (int f = 0; f < 8; ++f) {
        float bv = bias[cb + f * 16 + coll];
        #pragma unroll
        for (int r = 0; r < 2; ++r)
            #pragma unroll
            for (int g = 0; g < 4; ++g) {
                int m = mbase + r * 16 + (lane >> 4) * 4 + g;
                float v = acc[r][f][g] + bv;
                v = v > 0.f ? v : 0.f;
                Y[(size_t)m * HID + cb + f * 16 + coll] = __float2half(v);
            }
    }
}

// ------- conv_transpose: A + double-buffered B both in LDS, serial parity ----
template <int CIN, int COUT, int HIN, int R, int LOGH, int CF, int WAVES, int KSPLIT, int OH, int OB>
__global__ __launch_bounds__(WAVES * 64) void convt_lds3(
    const __half* __restrict__ X, const __half* __restrict__ Bt,
    const float* __restrict__ bias, __half* __restrict__ Y) {
    constexpr int HH = HIN * HIN;
    constexpr int KTOT = 4 * CIN;
    constexpr int CINS = CIN / KSPLIT;
    constexpr int NSTEPS = CINS / 32;
    constexpr int SL = CIN / 8;
    constexpr int SLB = CINS / 8;
    constexpr int T = WAVES * 64;
    constexpr int POS = WAVES * R * 16;
    constexpr int AROWS = POS;
    constexpr int AH = AROWS * CIN;
    constexpr int BROWS = CF * 16;
    constexpr int BH = BROWS * CINS;
    constexpr int SA = AROWS * SL;
    constexpr int SB = BROWS * SLB;
    constexpr int NSB = SB / T;
    constexpr int NST = 16 * KSPLIT;
    __shared__ _Float16 lds[AH + 2 * BH];

    int tid = threadIdx.x;
    int lane = tid & 63, w = tid >> 6;
    int kg = lane >> 4, coll = lane & 15;
    int n0 = blockIdx.x * (POS >> (2 * LOGH));
    int cbase = blockIdx.y * (CF * 16);
    int posbase = w * (R * 16);

    const __half* Xs = X + (size_t)n0 * HH * CIN;
    #pragma unroll
    for (int q = 0; q < SA / T; ++q) {
        int i = tid + q * T;
        int row = i / SL, slot = i % SL;
        f16x8 v = *(const f16x8*)(Xs + (size_t)i * 8);
        *(f16x8*)(&lds[row * CIN + ((slot ^ (row & 7)) * 8)]) = v;
    }
    f16x8 breg[NSB];
    #pragma unroll
    for (int q = 0; q < NSB; ++q) {
        int i = tid + q * T;
        int o = i / SLB, sl = i % SLB;
        breg[q] = *(const f16x8*)(Bt + ((size_t)(cbase + o) * KTOT) + sl * 8);
    }
    #pragma unroll
    for (int q = 0; q < NSB; ++q) {
        int i = tid + q * T;
        int o = i / SLB, sl = i % SLB;
        *(f16x8*)(&lds[AH + o * CINS + ((sl ^ (o & 7)) * 8)]) = breg[q];
    }
    __syncthreads();

    int posl[R]; bool okr[R][3], okc[R][3];
    #pragma unroll
    for (int r = 0; r < R; ++r) {
        int p = posbase + r * 16 + coll;
        posl[r] = p;
        int rem = p & (HH - 1);
        int a = rem >> LOGH, b = rem & (HIN - 1);
        #pragma unroll
        for (int s = 0; s < 3; ++s) {
            okr[r][s] = (unsigned)(a + s - 1) < (unsigned)HIN;
            okc[r][s] = (unsigned)(b + s - 1) < (unsigned)HIN;
        }
    }

    float bvv[CF];
    #pragma unroll
    for (int f = 0; f < CF; ++f) bvv[f] = bias[cbase + f * 16 + coll];

    #pragma unroll
    for (int par = 0; par < 4; ++par) {
        const int pi = par & 1, pj = par >> 1;
        f32x4 acc[R][CF];
        #pragma unroll
        for (int r = 0; r < R; ++r)
            #pragma unroll
            for (int f = 0; f < CF; ++f)
                acc[r][f] = (f32x4){bvv[f], bvv[f], bvv[f], bvv[f]};

        #pragma unroll
        for (int tt = 0; tt < 4 * KSPLIT; ++tt) {
            const int s = par * 4 * KSPLIT + tt;
            const int tap = tt / KSPLIT;
            const int kh = tt % KSPLIT;
            const int buf = s & 1;
            if (s + 1 < NST) {
                const int s2 = s + 1;
                const int par2 = s2 / (4 * KSPLIT);
                const int tt2 = s2 % (4 * KSPLIT);
                const int tap2 = tt2 / KSPLIT;
                const int kh2 = tt2 % KSPLIT;
                #pragma unroll
                for (int q = 0; q < NSB; ++q) {
                    int i = tid + q * T;
                    int o = i / SLB, sl = i % SLB;
                    breg[q] = *(const f16x8*)(Bt +
                        ((size_t)(par2 * COUT + cbase + o) * KTOT +
                         tap2 * CIN + kh2 * CINS) + sl * 8);
                }
            }
            const int iu = (tap >> 1) + pi, iv = (tap & 1) + pj;
            const int delta = (iu - 1) * HIN + (iv - 1);
            int rp[R]; bool ok[R];
            #pragma unroll
            for (int r = 0; r < R; ++r) {
                int t = posl[r] + delta;
                rp[r] = min(max(t, 0), AROWS - 1);
                ok[r] = okr[r][iu] && okc[r][iv];
            }
            const _Float16* Bl = &lds[AH + buf * BH];
            #pragma unroll
            for (int cc = 0; cc < NSTEPS; ++cc) {
                const int slB = cc * 4 + kg;
                const int slA = kh * SLB + slB;
                f16x8 b[CF];
                #pragma unroll
                for (int f = 0; f < CF; ++f)
                    b[f] = *(const f16x8*)(&Bl[(f * 16 + coll) * CINS +
                                               ((slB ^ (coll & 7)) * 8)]);
                f16x8 a[R];
                #pragma unroll
                for (int r = 0; r < R; ++r) {
                    f16x8 v = *(const f16x8*)(&lds[rp[r] * CIN +
                                                   ((slA ^ (rp[r] & 7)) * 8)]);
                    a[r] = ok[r] ? v : (f16x8){0, 0, 0, 0, 0, 0, 0, 0};
                }
                #pragma unroll
                for (int r = 0; r < R; ++r)
                    #pragma unroll
                    for (int f = 0; f < CF; ++f)
                        acc[r][f] = __builtin_amdgcn_mfma_f32_16x16x32_f16(
                            a[r], b[f], acc[r][f], 0, 0, 0);
            }
            if (s + 1 < NST) {
                #pragma unroll
                for (int q = 0; q < NSB; ++q) {
                    int i = tid + q * T;
                    int o = i / SLB, sl = i % SLB;
                    *(f16x8*)(&lds[AH + ((s + 1) & 1) * BH + o * CINS +
                                   ((sl ^ (o & 7)) * 8)]) = breg[q];
                }
                __syncthreads();
            }
        }

        #pragma unroll
        for (int r = 0; r < R; ++r) {
            #pragma unroll
            for (int g = 0; g < 4; ++g) {
                int p = posbase + r * 16 + kg * 4 + g;
                int ni = p >> (2 * LOGH);
                int rem = p & (HH - 1);
                int a2 = rem >> LOGH, b2 = rem & (HIN - 1);
                size_t ob = (((size_t)(n0 + ni) * OH + 2 * a2 + pi + OB) * OH +
                             2 * b2 + pj + OB) * COUT;
                #pragma unroll
                for (int f = 0; f < CF; ++f) {
                    float v = acc[r][f][g];
                    v = v > 0.f ? v : 0.f;
                    Y[ob + cbase + f * 16 + coll] = __float2half(v);
                }
            }
        }
    }
}

// ------- conv3+conv4 FUSED v2: swapped-operand conv3 + MFMA conv4 ------------
// conv3: acc = mfma(b, a) -> C[ch][site]: lane holds 4 consecutive channels of
// one site -> plane writes are f16x4 (8B), ~2-way banks.
// conv4: merged-shift MFMA: A=W4m (rows=parities), B=plane sites (per-lane
// shift via kg); 5 mfma per 16-site group per 16ch piece; no validity masks
// (border zeros). C rows 0..3 = parities -> kg==0 lanes do packed float2 out.
__global__ __launch_bounds__(256) void conv34_fused2(
    const __half* __restrict__ X, const __half* __restrict__ Bt,
    const float* __restrict__ bias3, const __half* __restrict__ W4m,
    const float* __restrict__ bias4, float* __restrict__ out) {
    constexpr int CIN = 64, HIN = 16, HH = 256, KTOT = 256;
    constexpr int SL = 8, T = 256, AROWS = 256, AH = AROWS * CIN;  // 16384 halves
    constexpr int BH = 32 * CIN;                                   // 2048 halves
    constexpr int PS = 1164;  // plane sub-piece stride (16B slots)
    __shared__ _Float16 lds[AH + 2 * BH];   // 40,960 B; 2-subpiece plane aliases

    int tid = threadIdx.x;
    int lane = tid & 63, w = tid >> 6;
    int kg = lane >> 4, coll = lane & 15;
    int n = blockIdx.x;
    int posbase = w * 64;

    // ---- stage A (whole 16x16x64 image) ----
    const __half* Xs = X + (size_t)n * HH * CIN;
    #pragma unroll
    for (int q = 0; q < 8; ++q) {
        int i = tid + q * T;
        int row = i / SL, slot = i % SL;
        f16x8 v = *(const f16x8*)(Xs + (size_t)i * 8);
        *(f16x8*)(&lds[row * CIN + ((slot ^ (row & 7)) * 8)]) = v;
    }
    // ---- stage B for stage 0 ----
    {
        int o = tid / SL, sl = tid % SL;
        f16x8 b0 = *(const f16x8*)(Bt + (size_t)o * KTOT + sl * 8);
        *(f16x8*)(&lds[AH + o * CIN + ((sl ^ (o & 7)) * 8)]) = b0;
    }
    __syncthreads();

    int posl[4]; bool okr[4][3], okc[4][3];
    #pragma unroll
    for (int r = 0; r < 4; ++r) {
        int p = posbase + r * 16 + coll;
        posl[r] = p;
        int a = p >> 4, b = p & 15;
        #pragma unroll
        for (int s = 0; s < 3; ++s) {
            okr[r][s] = (unsigned)(a + s - 1) < (unsigned)HIN;
            okc[r][s] = (unsigned)(b + s - 1) < (unsigned)HIN;
        }
    }

    // bias along C rows (channels): ch = f*16 + kg*4 + g
    f32x4 ib[2];
    #pragma unroll
    for (int f = 0; f < 2; ++f)
        #pragma unroll
        for (int g = 0; g < 4; ++g) ib[f][g] = bias3[f * 16 + kg * 4 + g];

    f32x4 acc[4][4][2];
    #pragma unroll
    for (int par = 0; par < 4; ++par)
        #pragma unroll
        for (int r = 0; r < 4; ++r) {
            acc[par][r][0] = ib[0];
            acc[par][r][1] = ib[1];
        }

    f16x8 breg;
    #pragma unroll
    for (int s = 0; s < 16; ++s) {
        const int par = s >> 2, tap = s & 3;
        const int pi = par & 1, pj = par >> 1;
        const int buf = s & 1;
        if (s + 1 < 16) {
            const int par2 = (s + 1) >> 2, tap2 = (s + 1) & 3;
            int o = tid / SL, sl = tid % SL;
            breg = *(const f16x8*)(Bt + ((size_t)(par2 * 32 + o) * KTOT +
                                         tap2 * CIN) + sl * 8);
        }
        const int iu = (tap >> 1) + pi, iv = (tap & 1) + pj;
        const int delta = (iu - 1) * HIN + (iv - 1);
        int rp[4]; bool ok[4];
        #pragma unroll
        for (int r = 0; r < 4; ++r) {
            int t2 = posl[r] + delta;
            rp[r] = min(max(t2, 0), AROWS - 1);
            ok[r] = okr[r][iu] && okc[r][iv];
        }
        const _Float16* Bl = &lds[AH + buf * BH];
        #pragma unroll
        for (int cc = 0; cc < 2; ++cc) {
            const int sl2 = cc * 4 + kg;
            f16x8 b[2];
            #pragma unroll
            for (int f = 0; f < 2; ++f)
                b[f] = *(const f16x8*)(&Bl[(f * 16 + coll) * CIN +
                                           ((sl2 ^ (coll & 7)) * 8)]);
            f16x8 a[4];
            #pragma unroll
            for (int r = 0; r < 4; ++r) {
                f16x8 v = *(const f16x8*)(&lds[rp[r] * CIN +
                                               ((sl2 ^ (rp[r] & 7)) * 8)]);
                a[r] = ok[r] ? v : (f16x8){0, 0, 0, 0, 0, 0, 0, 0};
            }
            // SWAPPED operands: C[ch][site]
            #pragma unroll
            for (int r = 0; r < 4; ++r)
                #pragma unroll
                for (int f = 0; f < 2; ++f)
                    acc[par][r][f] = __builtin_amdgcn_mfma_f32_16x16x32_f16(
                        b[f], a[r], acc[par][r][f], 0, 0, 0);
        }
        if (s + 1 < 16) {
            int o = tid / SL, sl = tid % SL;
            *(f16x8*)(&lds[AH + ((s + 1) & 1) * BH + o * CIN +
                           ((sl ^ (o & 7)) * 8)]) = breg;
            __syncthreads();
        }
    }
    __syncthreads();   // A/B regions now dead; plane buffer takes over

    // ---- conv4 phase (MFMA, merged shifts) ----
    int a_base = w * 8;                      // wave's 8 output-site rows
    int lane_base = a_base * 34 + coll;      // + a_loc*34 + bh*16 + shift
    float bv4 = bias4[0];
    f32x4 acc4[16];
    #pragma unroll
    for (int g2 = 0; g2 < 16; ++g2) acc4[g2] = (f32x4){bv4, bv4, bv4, bv4};

    #pragma unroll
    for (int f = 0; f < 2; ++f) {            // 16-ch piece
        // zero border ring (132 sites x 2 sub-pieces)
        for (int i = tid; i < 264; i += 256) {
            int posi = i >> 1, q = i & 1;
            int rr, sc;
            if (posi < 68) { rr = (posi < 34) ? 0 : 33; sc = posi % 34; }
            else { int e = posi - 68; rr = 1 + (e >> 1); sc = (e & 1) ? 33 : 0; }
            int site = rr * 34 + sc;
            int ss = site ^ ((site >> 3) & 7);
            *(f16x8*)(&lds[(q * PS + ss) * 8]) = (f16x8){0, 0, 0, 0, 0, 0, 0, 0};
        }
        // write relu'd conv3 output: lane holds ch f*16+kg*4+g at site posl[r]
        #pragma unroll
        for (int par = 0; par < 4; ++par) {
            const int pi = par & 1, pj = par >> 1;
            #pragma unroll
            for (int r = 0; r < 4; ++r) {
                int p = posl[r];
                int a2 = p >> 4, b2 = p & 15;
                int site = (2 * a2 + pi + 1) * 34 + (2 * b2 + pj + 1);
                int ss = site ^ ((site >> 3) & 7);
                f16x4 pv;
                #pragma unroll
                for (int g = 0; g < 4; ++g) {
                    float v = acc[par][r][f][g];
                    v = v > 0.f ? v : 0.f;
                    pv[g] = (_Float16)v;
                }
                *(f16x4*)(&lds[((kg >> 1) * PS + ss) * 8 + (kg & 1) * 4]) = pv;
            }
        }
        __syncthreads();
        // 5 shift-pair MFMAs per 16-site group
        #pragma unroll
        for (int sp = 0; sp < 5; ++sp) {
            f16x8 aw = *(const f16x8*)(W4m + ((size_t)(f * 5 + sp) * 16 + coll) * 32 + kg * 8);
            int s01 = sp * 2 + (kg >> 1);
            int bs = (s01 >= 9) ? 0 : (s01 / 3) * 34 + (s01 % 3);
            int lb = lane_base + bs + (kg & 1) * (PS * 0);  // kg&1 selects sub-piece below
            #pragma unroll
            for (int g2 = 0; g2 < 16; ++g2) {
                int a_loc = g2 >> 1, bh = g2 & 1;
                int site = lb + a_loc * 34 + bh * 16;
                int ss = site ^ ((site >> 3) & 7);
                f16x8 bx = *(const f16x8*)(&lds[((kg & 1) * PS + ss) * 8]);
                acc4[g2] = __builtin_amdgcn_mfma_f32_16x16x32_f16(aw, bx, acc4[g2], 0, 0, 0);
            }
        }
        if (f == 0) __syncthreads();   // before piece 1 overwrites the plane
    }
    // ---- output: kg==0 lanes hold rows 0..3 (= parities) for 16 sites ------
    if (kg == 0) {
        #pragma unroll
        for (int g2 = 0; g2 < 16; ++g2) {
            int a = a_base + (g2 >> 1);
            int bcol = (g2 & 1) * 32 + 2 * coll;
            float2 v0 = {acc4[g2][0], acc4[g2][2]};   // row 2a:   par0, par2
            float2 v1 = {acc4[g2][1], acc4[g2][3]};   // row 2a+1: par1, par3
            *(float2*)(&out[((size_t)n * 64 + 2 * a) * 64 + bcol]) = v0;
            *(float2*)(&out[((size_t)n * 64 + 2 * a + 1) * 64 + bcol]) = v1;
        }
    }
}

// ---------------- launch -----------------------------------------------------
extern "C" void kernel_launch(void* const* d_in, const int* in_sizes, int n_in,
                              void* d_out, int out_size, void* d_ws, size_t ws_size,
                              hipStream_t stream) {
    const float* angles   = (const float*)d_in[0];
    const float* item_rep = (const float*)d_in[1];
    const float* W        = (const float*)d_in[2];
    const float* bfc      = (const float*)d_in[3];
    const float* k1       = (const float*)d_in[4];
    const float* b1       = (const float*)d_in[5];
    const float* k2       = (const float*)d_in[6];
    const float* b2       = (const float*)d_in[7];
    const float* k3       = (const float*)d_in[8];
    const float* b3       = (const float*)d_in[9];
    const float* k4       = (const float*)d_in[10];
    const float* b4       = (const float*)d_in[11];

    char* ws = (char*)d_ws;
    float*  Ctab  = (float*)(ws + 0);                 //  32 KB
    __half* itemh = (__half*)(ws + 32768);            //   2 MB
    __half* Bt1   = (__half*)(ws + 2129920);          //   1 MB
    __half* Bt2   = (__half*)(ws + 3178496);          // 256 KB
    __half* Bt3   = (__half*)(ws + 3440640);          //  64 KB
    __half* W4m   = (__half*)(ws + 3506176);          //  10 KB
    __half* x0    = (__half*)(ws + 4194304);          //  16 MB -> 20,971,520
    __half* x1    = (__half*)(ws + 20971520);         //  32 MB -> 54,525,952
    __half* Wtfc  = (__half*)(ws + 121634816);        //   4 MB (dead region reuse)
    __half* x2    = (__half*)(ws + 155713536);        //  64 MB -> 222,822,400
    float*  out   = (float*)d_out;

    coef_kernel<<<1, 512, 0, stream>>>(Ctab);
    wigner_kernel<<<NBATCH, 64, 0, stream>>>(angles, item_rep, Ctab, itemh);
    fcw_prep2<<<dim3(KPAD / 64, HID / 64), 256, 0, stream>>>(W, Wtfc);
    convw_prep<256, 128><<<16, 256, 0, stream>>>(k1, Bt1);
    convw_prep<128, 64><<<16, 256, 0, stream>>>(k2, Bt2);
    convw_prep<64, 32><<<16, 256, 0, stream>>>(k3, Bt3);
    w4m_prep<<<20, 256, 0, stream>>>(k4, W4m);

    // FC: 2048x512 @ 512x4096 -> x0
    fc_mfma<<<dim3(16, 32), 256, 0, stream>>>(itemh, Wtfc, bfc, x0);
    // conv1: 4x4x256 -> 8x8x128  (R=1, CF=4, y=2 slices, k-split B stages)
    convt_lds3<256, 128, 4, 1, 2, 4, 4, 2, 8, 0><<<dim3(512, 2), 256, 0, stream>>>(x0, Bt1, b1, x1);
    // conv2: 8x8x128 -> 16x16x64 (R=2, CF=4) LDS = 32+32 = 64KB
    convt_lds3<128, 64, 8, 2, 3, 4, 4, 1, 16, 0><<<dim3(1024, 1), 256, 0, stream>>>(x1, Bt2, b2, x2);
    // conv3+conv4 fused v2: 16x16x64 -> (LDS) -> 64x64x1 fp32
    conv34_fused2<<<NBATCH, 256, 0, stream>>>(x2, Bt3, b3, W4m, b4, out);
}

// Round 13
// 312.954 us; speedup vs baseline: 1.1359x; 1.0031x over previous
//
#include <hip/hip_runtime.h>
#include <hip/hip_fp16.h>

#define DEG 6
#define RC 10
#define NBATCH 2048
#define FDIM 490
#define KPAD 512
#define HID 4096

typedef _Float16 f16x8 __attribute__((ext_vector_type(8)));
typedef _Float16 f16x4 __attribute__((ext_vector_type(4)));
typedef _Float16 f16x2 __attribute__((ext_vector_type(2)));
typedef float f32x4 __attribute__((ext_vector_type(4)));

// ---------------- Wigner coefficient tables (device, each call) --------------
__global__ void coef_kernel(float* __restrict__ Ctab) {
    int p = blockIdx.x * blockDim.x + threadIdx.x;
    if (p >= 455) return;
    const int poff[8] = {0, 1, 10, 35, 84, 165, 286, 455};
    const int loff[7] = {0, 1, 28, 153, 496, 1225, 2556};
    int l = 0;
    while (p >= poff[l + 1]) ++l;
    int idx = p - poff[l];
    int nn = 2 * l + 1;
    int mpi = idx / nn, mi = idx % nn;
    int mp = mpi - l, m = mi - l;
    double f[13];
    f[0] = 1.0;
    for (int i = 1; i < 13; ++i) f[i] = f[i - 1] * i;
    double pref = sqrt(f[l + mp] * f[l - mp] * f[l + m] * f[l - m]);
    float* row = Ctab + loff[l] + (size_t)(mpi * nn + mi) * nn;
    for (int q = 0; q < nn; ++q) row[q] = 0.f;
    int s0 = max(0, m - mp), s1 = min(l + m, l - mp);
    for (int s = s0; s <= s1; ++s) {
        int q = mp - m + 2 * s;
        double den = f[l + m - s] * f[s] * f[mp - m + s] * f[l - mp - s];
        double t = pref / den;
        if ((mp - m + s) & 1) t = -t;
        row[q] += (float)t;
    }
}

// ---------------- Wigner D + item projection -> fp16 item[n][512] ------------
__global__ __launch_bounds__(64) void wigner_kernel(
    const float* __restrict__ angles, const float* __restrict__ item_rep,
    const float* __restrict__ Ctab, __half* __restrict__ item_h) {
    int n = blockIdx.x, lane = threadIdx.x;
    float alpha = angles[n * 3 + 0], beta = angles[n * 3 + 1], gamma = angles[n * 3 + 2];
    float cb = cosf(beta * 0.5f), sb = sinf(beta * 0.5f);
    __shared__ float dsh[169], Dsh[169], Psh[13];
    __shared__ float ear[13], eai[13], egr[13], egi[13];
    const int loff[7] = {0, 1, 28, 153, 496, 1225, 2556};
    const float isq = 0.7071067811865476f;
    for (int l = 0; l <= DEG; ++l) {
        int nn = 2 * l + 1;
        if (lane < nn) {
            int q = lane;
            float pv = 1.f;
            for (int i = 0; i < 2 * l - q; ++i) pv *= cb;
            for (int i = 0; i < q; ++i) pv *= sb;
            Psh[q] = pv;
            float mm = (float)(lane - l);
            float sa, ca; sincosf(alpha * mm, &sa, &ca);
            ear[lane] = ca; eai[lane] = -sa;
            float sg, cg; sincosf(gamma * mm, &sg, &cg);
            egr[lane] = cg; egi[lane] = -sg;
        }
        __syncthreads();
        const float* Cl = Ctab + loff[l];
        for (int e = lane; e < nn * nn; e += 64) {
            float acc = 0.f;
            const float* cr = Cl + e * nn;
            for (int q = 0; q < nn; ++q) acc += cr[q] * Psh[q];
            dsh[e] = acc;
        }
        __syncthreads();
        for (int e = lane; e < nn * nn; e += 64) {
            int u = e / nn, v = e - u * nn;
            int bn, bi0, bi1; float br0, br1, bm0, bm1;
            int mu = u - l;
            if (mu == 0)      { bn = 1; bi0 = l; br0 = 1.f; bm0 = 0.f; bi1 = 0; br1 = 0.f; bm1 = 0.f; }
            else if (mu > 0)  { bn = 2; bi0 = l + mu; br0 = (mu & 1) ? -isq : isq; bm0 = 0.f;
                                bi1 = l - mu; br1 = isq; bm1 = 0.f; }
            else              { int mm2 = -mu; bn = 2; bi0 = l - mm2; br0 = 0.f; bm0 = isq;
                                bi1 = l + mm2; br1 = 0.f; bm1 = (mm2 & 1) ? isq : -isq; }
            int cn, ci0, ci1; float cr0, cr1, cm0, cm1;
            int nu = v - l;
            if (nu == 0)      { cn = 1; ci0 = l; cr0 = 1.f; cm0 = 0.f; ci1 = 0; cr1 = 0.f; cm1 = 0.f; }
            else if (nu > 0)  { cn = 2; ci0 = l + nu; cr0 = (nu & 1) ? -isq : isq; cm0 = 0.f;
                                ci1 = l - nu; cr1 = isq; cm1 = 0.f; }
            else              { int mm2 = -nu; cn = 2; ci0 = l - mm2; cr0 = 0.f; cm0 = -isq;
                                ci1 = l + mm2; cr1 = 0.f; cm1 = (mm2 & 1) ? -isq : isq; }
            float acc = 0.f;
            #pragma unroll
            for (int pb = 0; pb < 2; ++pb) {
                if (pb >= bn) break;
                int b = pb ? bi1 : bi0;
                float sr = pb ? br1 : br0, si = pb ? bm1 : bm0;
                float z1r = sr * ear[b] - si * eai[b];
                float z1i = sr * eai[b] + si * ear[b];
                #pragma unroll
                for (int pc = 0; pc < 2; ++pc) {
                    if (pc >= cn) break;
                    int c = pc ? ci1 : ci0;
                    float tr = pc ? cr1 : cr0, ti = pc ? cm1 : cm0;
                    float dv = dsh[b * nn + c];
                    float z2r = egr[c] * tr - egi[c] * ti;
                    float z2i = egr[c] * ti + egi[c] * tr;
                    acc += dv * (z1r * z2r - z1i * z2i);
                }
            }
            Dsh[e] = acc;
        }
        __syncthreads();
        for (int e = lane; e < nn * RC; e += 64) {
            int u = e / RC, r = e - u * RC;
            float acc = 0.f;
            for (int v = 0; v < nn; ++v)
                acc += Dsh[u * nn + v] * item_rep[(l * l + v) * RC + r];
            item_h[(size_t)n * KPAD + (l * l + u) * RC + r] = __float2half(acc);
        }
        __syncthreads();
    }
    if (lane < KPAD - FDIM)
        item_h[(size_t)n * KPAD + FDIM + lane] = __float2half(0.f);
}

// ------- FC weight prep (tiled transpose): W[490,4096] f32 -> Wt[4096][512] f16
__global__ __launch_bounds__(256) void fcw_prep2(const float* __restrict__ W,
                                                 __half* __restrict__ Wt) {
    __shared__ _Float16 tile[64][72];
    int k0 = blockIdx.x * 64;
    int o0 = blockIdx.y * 64;
    int tid = threadIdx.x;
    int tx = tid & 63, ty = tid >> 6;
    #pragma unroll
    for (int i = 0; i < 16; ++i) {
        int k = k0 + ty + i * 4;
        float v = (k < FDIM) ? W[(size_t)k * HID + o0 + tx] : 0.f;
        tile[ty + i * 4][tx] = (_Float16)v;
    }
    __syncthreads();
    #pragma unroll
    for (int p = 0; p < 2; ++p) {
        int idx = tid + p * 256;
        int ol = idx >> 3;
        int kl = (idx & 7) * 8;
        f16x8 v;
        #pragma unroll
        for (int e = 0; e < 8; ++e) v[e] = tile[kl + e][ol];
        *(f16x8*)(Wt + (size_t)(o0 + ol) * KPAD + k0 + kl) = v;
    }
}

// ---- conv weight prep: K[4][4][CIN][COUT] f32 -> Bt[par][COUT][4*CIN] f16 ---
template <int CIN, int COUT>
__global__ __launch_bounds__(256) void convw_prep(const float* __restrict__ K,
                                                  __half* __restrict__ Bt) {
    int par = blockIdx.x >> 2, tap = blockIdx.x & 3;
    int pi = par & 1, pj = par >> 1;
    int t1 = tap >> 1, t2 = tap & 1;
    int dh = pi + 2 * t1, dw = pj + 2 * t2;
    const float* Ks = K + (size_t)(dh * 4 + dw) * CIN * COUT;
    int o = threadIdx.x % COUT;
    int cg = threadIdx.x / COUT;
    constexpr int NG = 256 / COUT;
    for (int c0 = cg * 8; c0 < CIN; c0 += NG * 8) {
        f16x8 v;
        #pragma unroll
        for (int e = 0; e < 8; ++e) v[e] = (_Float16)Ks[(size_t)(c0 + e) * COUT + o];
        *(f16x8*)(Bt + ((size_t)par * COUT + o) * (4 * CIN) + tap * CIN + c0) = v;
    }
}

// ---- conv4 merged-shift weight table: W4m[piece(2)][sp(5)][row16][k32] f16 --
__global__ __launch_bounds__(256) void w4m_prep(const float* __restrict__ K4,
                                                __half* __restrict__ W4m) {
    int t = blockIdx.x * 256 + threadIdx.x;
    if (t >= 5120) return;
    int piece = t / 2560;
    int rem = t - piece * 2560;
    int sp = rem / 512;
    int rem2 = rem - sp * 512;
    int row = rem2 >> 5;
    int k = rem2 & 31;
    int h = k >> 4, c = k & 15;
    int s = sp * 2 + h;
    float v = 0.f;
    if (row < 4 && s < 9) {
        int iu = s / 3, iv = s % 3;
        int pi = row & 1, pj = row >> 1;
        int t1 = iu - pi, t2 = iv - pj;
        if (((unsigned)t1 < 2u) && ((unsigned)t2 < 2u)) {
            int dh = pi + 2 * t1, dw = pj + 2 * t2;
            v = K4[(dh * 4 + dw) * 32 + piece * 16 + c];
        }
    }
    W4m[t] = __float2half(v);
}

// ---------------- FC as MFMA GEMM: [2048x512] x [512x4096] + relu -> f16 -----
__global__ __launch_bounds__(256) void fc_mfma(
    const __half* __restrict__ A, const __half* __restrict__ Wt,
    const float* __restrict__ bias, __half* __restrict__ Y) {
    int lane = threadIdx.x & 63, wid = threadIdx.x >> 6;
    int job = blockIdx.x * 4 + wid;
    int mbase = job * 32;
    int cb = blockIdx.y * 128;
    int klane = (lane >> 4) * 8, coll = lane & 15;
    const __half* pA0 = A + (size_t)(mbase + coll) * KPAD + klane;
    const __half* pB0 = Wt + (size_t)(cb + coll) * KPAD + klane;
    f32x4 acc[2][8] = {};
    for (int s = 0; s < 16; ++s) {
        f16x8 a0 = *(const f16x8*)(pA0 + s * 32);
        f16x8 a1 = *(const f16x8*)(pA0 + 16 * KPAD + s * 32);
        #pragma unroll
        for (int f = 0; f < 8; ++f) {
            f16x8 b = *(const f16x8*)(pB0 + (size_t)f * 16 * KPAD + s * 32);
            acc[0][f] = __builtin_amdgcn_mfma_f32_16x16x32_f16(a0, b, acc[0][f], 0, 0, 0);
            acc[1][f] = __builtin_amdgcn_mfma_f32_16x16x32_f16(a1, b, acc[1][f], 0, 0, 0);
        }
    }
    #pragma unroll
    for (int f = 0; f < 8; ++f) {
        float bv = bias[cb + f * 16 + coll];
        #pragma unroll
        for (int r = 0; r < 2; ++r)
            #pragma unroll
            for (int g = 0; g < 4; ++g) {
                int m = mbase + r * 16 + (lane >> 4) * 4 + g;
                float v = acc[r][f][g] + bv;
                v = v > 0.f ? v : 0.f;
                Y[(size_t)m * HID + cb + f * 16 + coll] = __float2half(v);
            }
    }
}

// ------- conv_transpose: A + double-buffered B both in LDS, serial parity ----
template <int CIN, int COUT, int HIN, int R, int LOGH, int CF, int WAVES, int KSPLIT, int OH, int OB>
__global__ __launch_bounds__(WAVES * 64) void convt_lds3(
    const __half* __restrict__ X, const __half* __restrict__ Bt,
    const float* __restrict__ bias, __half* __restrict__ Y) {
    constexpr int HH = HIN * HIN;
    constexpr int KTOT = 4 * CIN;
    constexpr int CINS = CIN / KSPLIT;
    constexpr int NSTEPS = CINS / 32;
    constexpr int SL = CIN / 8;
    constexpr int SLB = CINS / 8;
    constexpr int T = WAVES * 64;
    constexpr int POS = WAVES * R * 16;
    constexpr int AROWS = POS;
    constexpr int AH = AROWS * CIN;
    constexpr int BROWS = CF * 16;
    constexpr int BH = BROWS * CINS;
    constexpr int SA = AROWS * SL;
    constexpr int SB = BROWS * SLB;
    constexpr int NSB = SB / T;
    constexpr int NST = 16 * KSPLIT;
    __shared__ _Float16 lds[AH + 2 * BH];

    int tid = threadIdx.x;
    int lane = tid & 63, w = tid >> 6;
    int kg = lane >> 4, coll = lane & 15;
    int n0 = blockIdx.x * (POS >> (2 * LOGH));
    int cbase = blockIdx.y * (CF * 16);
    int posbase = w * (R * 16);

    const __half* Xs = X + (size_t)n0 * HH * CIN;
    #pragma unroll
    for (int q = 0; q < SA / T; ++q) {
        int i = tid + q * T;
        int row = i / SL, slot = i % SL;
        f16x8 v = *(const f16x8*)(Xs + (size_t)i * 8);
        *(f16x8*)(&lds[row * CIN + ((slot ^ (row & 7)) * 8)]) = v;
    }
    f16x8 breg[NSB];
    #pragma unroll
    for (int q = 0; q < NSB; ++q) {
        int i = tid + q * T;
        int o = i / SLB, sl = i % SLB;
        breg[q] = *(const f16x8*)(Bt + ((size_t)(cbase + o) * KTOT) + sl * 8);
    }
    #pragma unroll
    for (int q = 0; q < NSB; ++q) {
        int i = tid + q * T;
        int o = i / SLB, sl = i % SLB;
        *(f16x8*)(&lds[AH + o * CINS + ((sl ^ (o & 7)) * 8)]) = breg[q];
    }
    __syncthreads();

    int posl[R]; bool okr[R][3], okc[R][3];
    #pragma unroll
    for (int r = 0; r < R; ++r) {
        int p = posbase + r * 16 + coll;
        posl[r] = p;
        int rem = p & (HH - 1);
        int a = rem >> LOGH, b = rem & (HIN - 1);
        #pragma unroll
        for (int s = 0; s < 3; ++s) {
            okr[r][s] = (unsigned)(a + s - 1) < (unsigned)HIN;
            okc[r][s] = (unsigned)(b + s - 1) < (unsigned)HIN;
        }
    }

    float bvv[CF];
    #pragma unroll
    for (int f = 0; f < CF; ++f) bvv[f] = bias[cbase + f * 16 + coll];

    #pragma unroll
    for (int par = 0; par < 4; ++par) {
        const int pi = par & 1, pj = par >> 1;
        f32x4 acc[R][CF];
        #pragma unroll
        for (int r = 0; r < R; ++r)
            #pragma unroll
            for (int f = 0; f < CF; ++f)
                acc[r][f] = (f32x4){bvv[f], bvv[f], bvv[f], bvv[f]};

        #pragma unroll
        for (int tt = 0; tt < 4 * KSPLIT; ++tt) {
            const int s = par * 4 * KSPLIT + tt;
            const int tap = tt / KSPLIT;
            const int kh = tt % KSPLIT;
            const int buf = s & 1;
            if (s + 1 < NST) {
                const int s2 = s + 1;
                const int par2 = s2 / (4 * KSPLIT);
                const int tt2 = s2 % (4 * KSPLIT);
                const int tap2 = tt2 / KSPLIT;
                const int kh2 = tt2 % KSPLIT;
                #pragma unroll
                for (int q = 0; q < NSB; ++q) {
                    int i = tid + q * T;
                    int o = i / SLB, sl = i % SLB;
                    breg[q] = *(const f16x8*)(Bt +
                        ((size_t)(par2 * COUT + cbase + o) * KTOT +
                         tap2 * CIN + kh2 * CINS) + sl * 8);
                }
            }
            const int iu = (tap >> 1) + pi, iv = (tap & 1) + pj;
            const int delta = (iu - 1) * HIN + (iv - 1);
            int rp[R]; bool ok[R];
            #pragma unroll
            for (int r = 0; r < R; ++r) {
                int t = posl[r] + delta;
                rp[r] = min(max(t, 0), AROWS - 1);
                ok[r] = okr[r][iu] && okc[r][iv];
            }
            const _Float16* Bl = &lds[AH + buf * BH];
            #pragma unroll
            for (int cc = 0; cc < NSTEPS; ++cc) {
                const int slB = cc * 4 + kg;
                const int slA = kh * SLB + slB;
                f16x8 b[CF];
                #pragma unroll
                for (int f = 0; f < CF; ++f)
                    b[f] = *(const f16x8*)(&Bl[(f * 16 + coll) * CINS +
                                               ((slB ^ (coll & 7)) * 8)]);
                f16x8 a[R];
                #pragma unroll
                for (int r = 0; r < R; ++r) {
                    f16x8 v = *(const f16x8*)(&lds[rp[r] * CIN +
                                                   ((slA ^ (rp[r] & 7)) * 8)]);
                    a[r] = ok[r] ? v : (f16x8){0, 0, 0, 0, 0, 0, 0, 0};
                }
                #pragma unroll
                for (int r = 0; r < R; ++r)
                    #pragma unroll
                    for (int f = 0; f < CF; ++f)
                        acc[r][f] = __builtin_amdgcn_mfma_f32_16x16x32_f16(
                            a[r], b[f], acc[r][f], 0, 0, 0);
            }
            if (s + 1 < NST) {
                #pragma unroll
                for (int q = 0; q < NSB; ++q) {
                    int i = tid + q * T;
                    int o = i / SLB, sl = i % SLB;
                    *(f16x8*)(&lds[AH + ((s + 1) & 1) * BH + o * CINS +
                                   ((sl ^ (o & 7)) * 8)]) = breg[q];
                }
                __syncthreads();
            }
        }

        #pragma unroll
        for (int r = 0; r < R; ++r) {
            #pragma unroll
            for (int g = 0; g < 4; ++g) {
                int p = posbase + r * 16 + kg * 4 + g;
                int ni = p >> (2 * LOGH);
                int rem = p & (HH - 1);
                int a2 = rem >> LOGH, b2 = rem & (HIN - 1);
                size_t ob = (((size_t)(n0 + ni) * OH + 2 * a2 + pi + OB) * OH +
                             2 * b2 + pj + OB) * COUT;
                #pragma unroll
                for (int f = 0; f < CF; ++f) {
                    float v = acc[r][f][g];
                    v = v > 0.f ? v : 0.f;
                    Y[ob + cbase + f * 16 + coll] = __float2half(v);
                }
            }
        }
    }
}

// ------- conv3+conv4 FUSED v3: per-PARITY B staging (4 stages, 3 barriers) ---
// B slice per parity = 32 out rows x 256 k (all 4 taps) = 16KB; double-buffered.
// LDS = A 32KB + 2x16KB B = 64KB. conv3 uses swapped-operand MFMA (C[ch][site]);
// conv4 = merged-shift MFMA (unchanged from validated v2).
__global__ __launch_bounds__(256) void conv34_fused3(
    const __half* __restrict__ X, const __half* __restrict__ Bt,
    const float* __restrict__ bias3, const __half* __restrict__ W4m,
    const float* __restrict__ bias4, float* __restrict__ out) {
    constexpr int CIN = 64, HIN = 16, HH = 256, KTOT = 256;
    constexpr int SL = 8, T = 256, AROWS = 256, AH = AROWS * CIN;  // 16384 halves
    constexpr int BH = 32 * KTOT;                                  // 8192 halves (16KB)
    constexpr int PS = 1164;  // plane sub-piece stride (16B slots)
    __shared__ _Float16 lds[AH + 2 * BH];   // 65,536 B

    int tid = threadIdx.x;
    int lane = tid & 63, w = tid >> 6;
    int kg = lane >> 4, coll = lane & 15;
    int n = blockIdx.x;
    int posbase = w * 64;

    // ---- stage A (whole 16x16x64 image) ----
    const __half* Xs = X + (size_t)n * HH * CIN;
    #pragma unroll
    for (int q = 0; q < 8; ++q) {
        int i = tid + q * T;
        int row = i / SL, slot = i % SL;
        f16x8 v = *(const f16x8*)(Xs + (size_t)i * 8);
        *(f16x8*)(&lds[row * CIN + ((slot ^ (row & 7)) * 8)]) = v;
    }
    // ---- stage B for parity 0 into buffer 0 (32 rows x 32 slots) ----
    #pragma unroll
    for (int q = 0; q < 4; ++q) {
        int i = tid + q * T;
        int o = i >> 5, sl = i & 31;
        f16x8 b0 = *(const f16x8*)(Bt + (size_t)o * KTOT + sl * 8);
        *(f16x8*)(&lds[AH + o * KTOT + ((sl ^ (o & 7)) * 8)]) = b0;
    }
    __syncthreads();

    int posl[4]; bool okr[4][3], okc[4][3];
    #pragma unroll
    for (int r = 0; r < 4; ++r) {
        int p = posbase + r * 16 + coll;
        posl[r] = p;
        int a = p >> 4, b = p & 15;
        #pragma unroll
        for (int s = 0; s < 3; ++s) {
            okr[r][s] = (unsigned)(a + s - 1) < (unsigned)HIN;
            okc[r][s] = (unsigned)(b + s - 1) < (unsigned)HIN;
        }
    }

    // bias along C rows (channels): ch = f*16 + kg*4 + g
    f32x4 ib[2];
    #pragma unroll
    for (int f = 0; f < 2; ++f)
        #pragma unroll
        for (int g = 0; g < 4; ++g) ib[f][g] = bias3[f * 16 + kg * 4 + g];

    f32x4 acc[4][4][2];
    #pragma unroll
    for (int par = 0; par < 4; ++par)
        #pragma unroll
        for (int r = 0; r < 4; ++r) {
            acc[par][r][0] = ib[0];
            acc[par][r][1] = ib[1];
        }

    // ---- conv3: 4 per-parity stages, each = 4 taps x 2 k-chunks ----
    f16x8 breg[4];
    #pragma unroll
    for (int par = 0; par < 4; ++par) {
        const int pi = par & 1, pj = par >> 1;
        const int buf = par & 1;
        // issue next parity's B loads early
        if (par < 3) {
            #pragma unroll
            for (int q = 0; q < 4; ++q) {
                int i = tid + q * T;
                int o = i >> 5, sl = i & 31;
                breg[q] = *(const f16x8*)(Bt + ((size_t)((par + 1) * 32 + o) * KTOT) + sl * 8);
            }
        }
        const _Float16* Bl = &lds[AH + buf * BH];
        #pragma unroll
        for (int tap = 0; tap < 4; ++tap) {
            const int iu = (tap >> 1) + pi, iv = (tap & 1) + pj;
            const int delta = (iu - 1) * HIN + (iv - 1);
            int rp[4]; bool ok[4];
            #pragma unroll
            for (int r = 0; r < 4; ++r) {
                int t2 = posl[r] + delta;
                rp[r] = min(max(t2, 0), AROWS - 1);
                ok[r] = okr[r][iu] && okc[r][iv];
            }
            #pragma unroll
            for (int cc = 0; cc < 2; ++cc) {
                const int slA = cc * 4 + kg;            // k within CIN=64
                const int slB = tap * 8 + slA;          // k within KTOT=256
                f16x8 b[2];
                #pragma unroll
                for (int f = 0; f < 2; ++f)
                    b[f] = *(const f16x8*)(&Bl[(f * 16 + coll) * KTOT +
                                               ((slB ^ (coll & 7)) * 8)]);
                f16x8 a[4];
                #pragma unroll
                for (int r = 0; r < 4; ++r) {
                    f16x8 v = *(const f16x8*)(&lds[rp[r] * CIN +
                                                   ((slA ^ (rp[r] & 7)) * 8)]);
                    a[r] = ok[r] ? v : (f16x8){0, 0, 0, 0, 0, 0, 0, 0};
                }
                // SWAPPED operands: C[ch][site]
                #pragma unroll
                for (int r = 0; r < 4; ++r)
                    #pragma unroll
                    for (int f = 0; f < 2; ++f)
                        acc[par][r][f] = __builtin_amdgcn_mfma_f32_16x16x32_f16(
                            b[f], a[r], acc[par][r][f], 0, 0, 0);
            }
        }
        // write-late into the other buffer, one barrier per parity
        if (par < 3) {
            #pragma unroll
            for (int q = 0; q < 4; ++q) {
                int i = tid + q * T;
                int o = i >> 5, sl = i & 31;
                *(f16x8*)(&lds[AH + ((par + 1) & 1) * BH + o * KTOT +
                               ((sl ^ (o & 7)) * 8)]) = breg[q];
            }
            __syncthreads();
        }
    }
    __syncthreads();   // A/B regions now dead; plane buffer takes over

    // ---- conv4 phase (MFMA, merged shifts) — identical to validated v2 ----
    int a_base = w * 8;
    int lane_base = a_base * 34 + coll;
    float bv4 = bias4[0];
    f32x4 acc4[16];
    #pragma unroll
    for (int g2 = 0; g2 < 16; ++g2) acc4[g2] = (f32x4){bv4, bv4, bv4, bv4};

    #pragma unroll
    for (int f = 0; f < 2; ++f) {            // 16-ch piece
        for (int i = tid; i < 264; i += 256) {
            int posi = i >> 1, q = i & 1;
            int rr, sc;
            if (posi < 68) { rr = (posi < 34) ? 0 : 33; sc = posi % 34; }
            else { int e = posi - 68; rr = 1 + (e >> 1); sc = (e & 1) ? 33 : 0; }
            int site = rr * 34 + sc;
            int ss = site ^ ((site >> 3) & 7);
            *(f16x8*)(&lds[(q * PS + ss) * 8]) = (f16x8){0, 0, 0, 0, 0, 0, 0, 0};
        }
        #pragma unroll
        for (int par = 0; par < 4; ++par) {
            const int pi = par & 1, pj = par >> 1;
            #pragma unroll
            for (int r = 0; r < 4; ++r) {
                int p = posl[r];
                int a2 = p >> 4, b2 = p & 15;
                int site = (2 * a2 + pi + 1) * 34 + (2 * b2 + pj + 1);
                int ss = site ^ ((site >> 3) & 7);
                f16x4 pv;
                #pragma unroll
                for (int g = 0; g < 4; ++g) {
                    float v = acc[par][r][f][g];
                    v = v > 0.f ? v : 0.f;
                    pv[g] = (_Float16)v;
                }
                *(f16x4*)(&lds[((kg >> 1) * PS + ss) * 8 + (kg & 1) * 4]) = pv;
            }
        }
        __syncthreads();
        #pragma unroll
        for (int sp = 0; sp < 5; ++sp) {
            f16x8 aw = *(const f16x8*)(W4m + ((size_t)(f * 5 + sp) * 16 + coll) * 32 + kg * 8);
            int s01 = sp * 2 + (kg >> 1);
            int bs = (s01 >= 9) ? 0 : (s01 / 3) * 34 + (s01 % 3);
            int lb = lane_base + bs;
            #pragma unroll
            for (int g2 = 0; g2 < 16; ++g2) {
                int a_loc = g2 >> 1, bh = g2 & 1;
                int site = lb + a_loc * 34 + bh * 16;
                int ss = site ^ ((site >> 3) & 7);
                f16x8 bx = *(const f16x8*)(&lds[((kg & 1) * PS + ss) * 8]);
                acc4[g2] = __builtin_amdgcn_mfma_f32_16x16x32_f16(aw, bx, acc4[g2], 0, 0, 0);
            }
        }
        if (f == 0) __syncthreads();
    }
    if (kg == 0) {
        #pragma unroll
        for (int g2 = 0; g2 < 16; ++g2) {
            int a = a_base + (g2 >> 1);
            int bcol = (g2 & 1) * 32 + 2 * coll;
            float2 v0 = {acc4[g2][0], acc4[g2][2]};
            float2 v1 = {acc4[g2][1], acc4[g2][3]};
            *(float2*)(&out[((size_t)n * 64 + 2 * a) * 64 + bcol]) = v0;
            *(float2*)(&out[((size_t)n * 64 + 2 * a + 1) * 64 + bcol]) = v1;
        }
    }
}

// ---------------- launch -----------------------------------------------------
extern "C" void kernel_launch(void* const* d_in, const int* in_sizes, int n_in,
                              void* d_out, int out_size, void* d_ws, size_t ws_size,
                              hipStream_t stream) {
    const float* angles   = (const float*)d_in[0];
    const float* item_rep = (const float*)d_in[1];
    const float* W        = (const float*)d_in[2];
    const float* bfc      = (const float*)d_in[3];
    const float* k1       = (const float*)d_in[4];
    const float* b1       = (const float*)d_in[5];
    const float* k2       = (const float*)d_in[6];
    const float* b2       = (const float*)d_in[7];
    const float* k3       = (const float*)d_in[8];
    const float* b3       = (const float*)d_in[9];
    const float* k4       = (const float*)d_in[10];
    const float* b4       = (const float*)d_in[11];

    char* ws = (char*)d_ws;
    float*  Ctab  = (float*)(ws + 0);                 //  32 KB
    __half* itemh = (__half*)(ws + 32768);            //   2 MB
    __half* Bt1   = (__half*)(ws + 2129920);          //   1 MB
    __half* Bt2   = (__half*)(ws + 3178496);          // 256 KB
    __half* Bt3   = (__half*)(ws + 3440640);          //  64 KB
    __half* W4m   = (__half*)(ws + 3506176);          //  10 KB
    __half* x0    = (__half*)(ws + 4194304);          //  16 MB -> 20,971,520
    __half* x1    = (__half*)(ws + 20971520);         //  32 MB -> 54,525,952
    __half* Wtfc  = (__half*)(ws + 121634816);        //   4 MB (dead region reuse)
    __half* x2    = (__half*)(ws + 155713536);        //  64 MB -> 222,822,400
    float*  out   = (float*)d_out;

    coef_kernel<<<1, 512, 0, stream>>>(Ctab);
    wigner_kernel<<<NBATCH, 64, 0, stream>>>(angles, item_rep, Ctab, itemh);
    fcw_prep2<<<dim3(KPAD / 64, HID / 64), 256, 0, stream>>>(W, Wtfc);
    convw_prep<256, 128><<<16, 256, 0, stream>>>(k1, Bt1);
    convw_prep<128, 64><<<16, 256, 0, stream>>>(k2, Bt2);
    convw_prep<64, 32><<<16, 256, 0, stream>>>(k3, Bt3);
    w4m_prep<<<20, 256, 0, stream>>>(k4, W4m);

    // FC: 2048x512 @ 512x4096 -> x0
    fc_mfma<<<dim3(16, 32), 256, 0, stream>>>(itemh, Wtfc, bfc, x0);
    // conv1: 4x4x256 -> 8x8x128  (R=1, CF=4, y=2 slices, k-split B stages)
    convt_lds3<256, 128, 4, 1, 2, 4, 4, 2, 8, 0><<<dim3(512, 2), 256, 0, stream>>>(x0, Bt1, b1, x1);
    // conv2: 8x8x128 -> 16x16x64 (R=2, CF=4) LDS = 32+32 = 64KB
    convt_lds3<128, 64, 8, 2, 3, 4, 4, 1, 16, 0><<<dim3(1024, 1), 256, 0, stream>>>(x1, Bt2, b2, x2);
    // conv3+conv4 fused v3 (per-parity B stages): 16x16x64 -> (LDS) -> 64x64x1
    conv34_fused3<<<NBATCH, 256, 0, stream>>>(x2, Bt3, b3, W4m, b4, out);
}

// Round 14
// 285.495 us; speedup vs baseline: 1.2452x; 1.0962x over previous
//
#include <hip/hip_runtime.h>
#include <hip/hip_fp16.h>

#define DEG 6
#define RC 10
#define NBATCH 2048
#define FDIM 490
#define KPAD 512
#define HID 4096

typedef _Float16 f16x8 __attribute__((ext_vector_type(8)));
typedef _Float16 f16x4 __attribute__((ext_vector_type(4)));
typedef _Float16 f16x2 __attribute__((ext_vector_type(2)));
typedef float f32x4 __attribute__((ext_vector_type(4)));

// ---------------- Wigner coefficient tables (device, each call) --------------
__global__ void coef_kernel(float* __restrict__ Ctab) {
    int p = blockIdx.x * blockDim.x + threadIdx.x;
    if (p >= 455) return;
    const int poff[8] = {0, 1, 10, 35, 84, 165, 286, 455};
    const int loff[7] = {0, 1, 28, 153, 496, 1225, 2556};
    int l = 0;
    while (p >= poff[l + 1]) ++l;
    int idx = p - poff[l];
    int nn = 2 * l + 1;
    int mpi = idx / nn, mi = idx % nn;
    int mp = mpi - l, m = mi - l;
    double f[13];
    f[0] = 1.0;
    for (int i = 1; i < 13; ++i) f[i] = f[i - 1] * i;
    double pref = sqrt(f[l + mp] * f[l - mp] * f[l + m] * f[l - m]);
    float* row = Ctab + loff[l] + (size_t)(mpi * nn + mi) * nn;
    for (int q = 0; q < nn; ++q) row[q] = 0.f;
    int s0 = max(0, m - mp), s1 = min(l + m, l - mp);
    for (int s = s0; s <= s1; ++s) {
        int q = mp - m + 2 * s;
        double den = f[l + m - s] * f[s] * f[mp - m + s] * f[l - mp - s];
        double t = pref / den;
        if ((mp - m + s) & 1) t = -t;
        row[q] += (float)t;
    }
}

// ---------------- Wigner D + item projection -> fp16 item[n][512] ------------
__global__ __launch_bounds__(64) void wigner_kernel(
    const float* __restrict__ angles, const float* __restrict__ item_rep,
    const float* __restrict__ Ctab, __half* __restrict__ item_h) {
    int n = blockIdx.x, lane = threadIdx.x;
    float alpha = angles[n * 3 + 0], beta = angles[n * 3 + 1], gamma = angles[n * 3 + 2];
    float cb = cosf(beta * 0.5f), sb = sinf(beta * 0.5f);
    __shared__ float dsh[169], Dsh[169], Psh[13];
    __shared__ float ear[13], eai[13], egr[13], egi[13];
    const int loff[7] = {0, 1, 28, 153, 496, 1225, 2556};
    const float isq = 0.7071067811865476f;
    for (int l = 0; l <= DEG; ++l) {
        int nn = 2 * l + 1;
        if (lane < nn) {
            int q = lane;
            float pv = 1.f;
            for (int i = 0; i < 2 * l - q; ++i) pv *= cb;
            for (int i = 0; i < q; ++i) pv *= sb;
            Psh[q] = pv;
            float mm = (float)(lane - l);
            float sa, ca; sincosf(alpha * mm, &sa, &ca);
            ear[lane] = ca; eai[lane] = -sa;
            float sg, cg; sincosf(gamma * mm, &sg, &cg);
            egr[lane] = cg; egi[lane] = -sg;
        }
        __syncthreads();
        const float* Cl = Ctab + loff[l];
        for (int e = lane; e < nn * nn; e += 64) {
            float acc = 0.f;
            const float* cr = Cl + e * nn;
            for (int q = 0; q < nn; ++q) acc += cr[q] * Psh[q];
            dsh[e] = acc;
        }
        __syncthreads();
        for (int e = lane; e < nn * nn; e += 64) {
            int u = e / nn, v = e - u * nn;
            int bn, bi0, bi1; float br0, br1, bm0, bm1;
            int mu = u - l;
            if (mu == 0)      { bn = 1; bi0 = l; br0 = 1.f; bm0 = 0.f; bi1 = 0; br1 = 0.f; bm1 = 0.f; }
            else if (mu > 0)  { bn = 2; bi0 = l + mu; br0 = (mu & 1) ? -isq : isq; bm0 = 0.f;
                                bi1 = l - mu; br1 = isq; bm1 = 0.f; }
            else              { int mm2 = -mu; bn = 2; bi0 = l - mm2; br0 = 0.f; bm0 = isq;
                                bi1 = l + mm2; br1 = 0.f; bm1 = (mm2 & 1) ? isq : -isq; }
            int cn, ci0, ci1; float cr0, cr1, cm0, cm1;
            int nu = v - l;
            if (nu == 0)      { cn = 1; ci0 = l; cr0 = 1.f; cm0 = 0.f; ci1 = 0; cr1 = 0.f; cm1 = 0.f; }
            else if (nu > 0)  { cn = 2; ci0 = l + nu; cr0 = (nu & 1) ? -isq : isq; cm0 = 0.f;
                                ci1 = l - nu; cr1 = isq; cm1 = 0.f; }
            else              { int mm2 = -nu; cn = 2; ci0 = l - mm2; cr0 = 0.f; cm0 = -isq;
                                ci1 = l + mm2; cr1 = 0.f; cm1 = (mm2 & 1) ? -isq : isq; }
            float acc = 0.f;
            #pragma unroll
            for (int pb = 0; pb < 2; ++pb) {
                if (pb >= bn) break;
                int b = pb ? bi1 : bi0;
                float sr = pb ? br1 : br0, si = pb ? bm1 : bm0;
                float z1r = sr * ear[b] - si * eai[b];
                float z1i = sr * eai[b] + si * ear[b];
                #pragma unroll
                for (int pc = 0; pc < 2; ++pc) {
                    if (pc >= cn) break;
                    int c = pc ? ci1 : ci0;
                    float tr = pc ? cr1 : cr0, ti = pc ? cm1 : cm0;
                    float dv = dsh[b * nn + c];
                    float z2r = egr[c] * tr - egi[c] * ti;
                    float z2i = egr[c] * ti + egi[c] * tr;
                    acc += dv * (z1r * z2r - z1i * z2i);
                }
            }
            Dsh[e] = acc;
        }
        __syncthreads();
        for (int e = lane; e < nn * RC; e += 64) {
            int u = e / RC, r = e - u * RC;
            float acc = 0.f;
            for (int v = 0; v < nn; ++v)
                acc += Dsh[u * nn + v] * item_rep[(l * l + v) * RC + r];
            item_h[(size_t)n * KPAD + (l * l + u) * RC + r] = __float2half(acc);
        }
        __syncthreads();
    }
    if (lane < KPAD - FDIM)
        item_h[(size_t)n * KPAD + FDIM + lane] = __float2half(0.f);
}

// ------- FC weight prep (tiled transpose): W[490,4096] f32 -> Wt[4096][512] f16
__global__ __launch_bounds__(256) void fcw_prep2(const float* __restrict__ W,
                                                 __half* __restrict__ Wt) {
    __shared__ _Float16 tile[64][72];
    int k0 = blockIdx.x * 64;
    int o0 = blockIdx.y * 64;
    int tid = threadIdx.x;
    int tx = tid & 63, ty = tid >> 6;
    #pragma unroll
    for (int i = 0; i < 16; ++i) {
        int k = k0 + ty + i * 4;
        float v = (k < FDIM) ? W[(size_t)k * HID + o0 + tx] : 0.f;
        tile[ty + i * 4][tx] = (_Float16)v;
    }
    __syncthreads();
    #pragma unroll
    for (int p = 0; p < 2; ++p) {
        int idx = tid + p * 256;
        int ol = idx >> 3;
        int kl = (idx & 7) * 8;
        f16x8 v;
        #pragma unroll
        for (int e = 0; e < 8; ++e) v[e] = tile[kl + e][ol];
        *(f16x8*)(Wt + (size_t)(o0 + ol) * KPAD + k0 + kl) = v;
    }
}

// ---- conv weight prep: K[4][4][CIN][COUT] f32 -> Bt[par][COUT][4*CIN] f16 ---
template <int CIN, int COUT>
__global__ __launch_bounds__(256) void convw_prep(const float* __restrict__ K,
                                                  __half* __restrict__ Bt) {
    int par = blockIdx.x >> 2, tap = blockIdx.x & 3;
    int pi = par & 1, pj = par >> 1;
    int t1 = tap >> 1, t2 = tap & 1;
    int dh = pi + 2 * t1, dw = pj + 2 * t2;
    const float* Ks = K + (size_t)(dh * 4 + dw) * CIN * COUT;
    int o = threadIdx.x % COUT;
    int cg = threadIdx.x / COUT;
    constexpr int NG = 256 / COUT;
    for (int c0 = cg * 8; c0 < CIN; c0 += NG * 8) {
        f16x8 v;
        #pragma unroll
        for (int e = 0; e < 8; ++e) v[e] = (_Float16)Ks[(size_t)(c0 + e) * COUT + o];
        *(f16x8*)(Bt + ((size_t)par * COUT + o) * (4 * CIN) + tap * CIN + c0) = v;
    }
}

// ---- conv4 merged-shift weight table: W4m[piece(2)][sp(5)][row16][k32] f16 --
__global__ __launch_bounds__(256) void w4m_prep(const float* __restrict__ K4,
                                                __half* __restrict__ W4m) {
    int t = blockIdx.x * 256 + threadIdx.x;
    if (t >= 5120) return;
    int piece = t / 2560;
    int rem = t - piece * 2560;
    int sp = rem / 512;
    int rem2 = rem - sp * 512;
    int row = rem2 >> 5;
    int k = rem2 & 31;
    int h = k >> 4, c = k & 15;
    int s = sp * 2 + h;
    float v = 0.f;
    if (row < 4 && s < 9) {
        int iu = s / 3, iv = s % 3;
        int pi = row & 1, pj = row >> 1;
        int t1 = iu - pi, t2 = iv - pj;
        if (((unsigned)t1 < 2u) && ((unsigned)t2 < 2u)) {
            int dh = pi + 2 * t1, dw = pj + 2 * t2;
            v = K4[(dh * 4 + dw) * 32 + piece * 16 + c];
        }
    }
    W4m[t] = __float2half(v);
}

// ---------------- FC as MFMA GEMM: [2048x512] x [512x4096] + relu -> f16 -----
__global__ __launch_bounds__(256) void fc_mfma(
    const __half* __restrict__ A, const __half* __restrict__ Wt,
    const float* __restrict__ bias, __half* __restrict__ Y) {
    int lane = threadIdx.x & 63, wid = threadIdx.x >> 6;
    int job = blockIdx.x * 4 + wid;
    int mbase = job * 32;
    int cb = blockIdx.y * 128;
    int klane = (lane >> 4) * 8, coll = lane & 15;
    const __half* pA0 = A + (size_t)(mbase + coll) * KPAD + klane;
    const __half* pB0 = Wt + (size_t)(cb + coll) * KPAD + klane;
    f32x4 acc[2][8] = {};
    for (int s = 0; s < 16; ++s) {
        f16x8 a0 = *(const f16x8*)(pA0 + s * 32);
        f16x8 a1 = *(const f16x8*)(pA0 + 16 * KPAD + s * 32);
        #pragma unroll
        for (int f = 0; f < 8; ++f) {
            f16x8 b = *(const f16x8*)(pB0 + (size_t)f * 16 * KPAD + s * 32);
            acc[0][f] = __builtin_amdgcn_mfma_f32_16x16x32_f16(a0, b, acc[0][f], 0, 0, 0);
            acc[1][f] = __builtin_amdgcn_mfma_f32_16x16x32_f16(a1, b, acc[1][f], 0, 0, 0);
        }
    }
    #pragma unroll
    for (int f = 0; f < 8; ++f) {
        float bv = bias[cb + f * 16 + coll];
        #pragma unroll
        for (int r = 0; r < 2; ++r)
            #pragma unroll
            for (int g = 0; g < 4; ++g) {
                int m = mbase + r * 16 + (lane >> 4) * 4 + g;
                float v = acc[r][f][g] + bv;
                v = v > 0.f ? v : 0.f;
                Y[(size_t)m * HID + cb + f * 16 + coll] = __float2half(v);
            }
    }
}

// ------- conv_transpose: A + double-buffered B both in LDS, serial parity ----
template <int CIN, int COUT, int HIN, int R, int LOGH, int CF, int WAVES, int KSPLIT, int OH, int OB>
__global__ __launch_bounds__(WAVES * 64) void convt_lds3(
    const __half* __restrict__ X, const __half* __restrict__ Bt,
    const float* __restrict__ bias, __half* __restrict__ Y) {
    constexpr int HH = HIN * HIN;
    constexpr int KTOT = 4 * CIN;
    constexpr int CINS = CIN / KSPLIT;
    constexpr int NSTEPS = CINS / 32;
    constexpr int SL = CIN / 8;
    constexpr int SLB = CINS / 8;
    constexpr int T = WAVES * 64;
    constexpr int POS = WAVES * R * 16;
    constexpr int AROWS = POS;
    constexpr int AH = AROWS * CIN;
    constexpr int BROWS = CF * 16;
    constexpr int BH = BROWS * CINS;
    constexpr int SA = AROWS * SL;
    constexpr int SB = BROWS * SLB;
    constexpr int NSB = SB / T;
    constexpr int NST = 16 * KSPLIT;
    __shared__ _Float16 lds[AH + 2 * BH];

    int tid = threadIdx.x;
    int lane = tid & 63, w = tid >> 6;
    int kg = lane >> 4, coll = lane & 15;
    int n0 = blockIdx.x * (POS >> (2 * LOGH));
    int cbase = blockIdx.y * (CF * 16);
    int posbase = w * (R * 16);

    const __half* Xs = X + (size_t)n0 * HH * CIN;
    #pragma unroll
    for (int q = 0; q < SA / T; ++q) {
        int i = tid + q * T;
        int row = i / SL, slot = i % SL;
        f16x8 v = *(const f16x8*)(Xs + (size_t)i * 8);
        *(f16x8*)(&lds[row * CIN + ((slot ^ (row & 7)) * 8)]) = v;
    }
    f16x8 breg[NSB];
    #pragma unroll
    for (int q = 0; q < NSB; ++q) {
        int i = tid + q * T;
        int o = i / SLB, sl = i % SLB;
        breg[q] = *(const f16x8*)(Bt + ((size_t)(cbase + o) * KTOT) + sl * 8);
    }
    #pragma unroll
    for (int q = 0; q < NSB; ++q) {
        int i = tid + q * T;
        int o = i / SLB, sl = i % SLB;
        *(f16x8*)(&lds[AH + o * CINS + ((sl ^ (o & 7)) * 8)]) = breg[q];
    }
    __syncthreads();

    int posl[R]; bool okr[R][3], okc[R][3];
    #pragma unroll
    for (int r = 0; r < R; ++r) {
        int p = posbase + r * 16 + coll;
        posl[r] = p;
        int rem = p & (HH - 1);
        int a = rem >> LOGH, b = rem & (HIN - 1);
        #pragma unroll
        for (int s = 0; s < 3; ++s) {
            okr[r][s] = (unsigned)(a + s - 1) < (unsigned)HIN;
            okc[r][s] = (unsigned)(b + s - 1) < (unsigned)HIN;
        }
    }

    float bvv[CF];
    #pragma unroll
    for (int f = 0; f < CF; ++f) bvv[f] = bias[cbase + f * 16 + coll];

    #pragma unroll
    for (int par = 0; par < 4; ++par) {
        const int pi = par & 1, pj = par >> 1;
        f32x4 acc[R][CF];
        #pragma unroll
        for (int r = 0; r < R; ++r)
            #pragma unroll
            for (int f = 0; f < CF; ++f)
                acc[r][f] = (f32x4){bvv[f], bvv[f], bvv[f], bvv[f]};

        #pragma unroll
        for (int tt = 0; tt < 4 * KSPLIT; ++tt) {
            const int s = par * 4 * KSPLIT + tt;
            const int tap = tt / KSPLIT;
            const int kh = tt % KSPLIT;
            const int buf = s & 1;
            if (s + 1 < NST) {
                const int s2 = s + 1;
                const int par2 = s2 / (4 * KSPLIT);
                const int tt2 = s2 % (4 * KSPLIT);
                const int tap2 = tt2 / KSPLIT;
                const int kh2 = tt2 % KSPLIT;
                #pragma unroll
                for (int q = 0; q < NSB; ++q) {
                    int i = tid + q * T;
                    int o = i / SLB, sl = i % SLB;
                    breg[q] = *(const f16x8*)(Bt +
                        ((size_t)(par2 * COUT + cbase + o) * KTOT +
                         tap2 * CIN + kh2 * CINS) + sl * 8);
                }
            }
            const int iu = (tap >> 1) + pi, iv = (tap & 1) + pj;
            const int delta = (iu - 1) * HIN + (iv - 1);
            int rp[R]; bool ok[R];
            #pragma unroll
            for (int r = 0; r < R; ++r) {
                int t = posl[r] + delta;
                rp[r] = min(max(t, 0), AROWS - 1);
                ok[r] = okr[r][iu] && okc[r][iv];
            }
            const _Float16* Bl = &lds[AH + buf * BH];
            #pragma unroll
            for (int cc = 0; cc < NSTEPS; ++cc) {
                const int slB = cc * 4 + kg;
                const int slA = kh * SLB + slB;
                f16x8 b[CF];
                #pragma unroll
                for (int f = 0; f < CF; ++f)
                    b[f] = *(const f16x8*)(&Bl[(f * 16 + coll) * CINS +
                                               ((slB ^ (coll & 7)) * 8)]);
                f16x8 a[R];
                #pragma unroll
                for (int r = 0; r < R; ++r) {
                    f16x8 v = *(const f16x8*)(&lds[rp[r] * CIN +
                                                   ((slA ^ (rp[r] & 7)) * 8)]);
                    a[r] = ok[r] ? v : (f16x8){0, 0, 0, 0, 0, 0, 0, 0};
                }
                #pragma unroll
                for (int r = 0; r < R; ++r)
                    #pragma unroll
                    for (int f = 0; f < CF; ++f)
                        acc[r][f] = __builtin_amdgcn_mfma_f32_16x16x32_f16(
                            a[r], b[f], acc[r][f], 0, 0, 0);
            }
            if (s + 1 < NST) {
                #pragma unroll
                for (int q = 0; q < NSB; ++q) {
                    int i = tid + q * T;
                    int o = i / SLB, sl = i % SLB;
                    *(f16x8*)(&lds[AH + ((s + 1) & 1) * BH + o * CINS +
                                   ((sl ^ (o & 7)) * 8)]) = breg[q];
                }
                __syncthreads();
            }
        }

        #pragma unroll
        for (int r = 0; r < R; ++r) {
            #pragma unroll
            for (int g = 0; g < 4; ++g) {
                int p = posbase + r * 16 + kg * 4 + g;
                int ni = p >> (2 * LOGH);
                int rem = p & (HH - 1);
                int a2 = rem >> LOGH, b2 = rem & (HIN - 1);
                size_t ob = (((size_t)(n0 + ni) * OH + 2 * a2 + pi + OB) * OH +
                             2 * b2 + pj + OB) * COUT;
                #pragma unroll
                for (int f = 0; f < CF; ++f) {
                    float v = acc[r][f][g];
                    v = v > 0.f ? v : 0.f;
                    Y[ob + cbase + f * 16 + coll] = __float2half(v);
                }
            }
        }
    }
}

// ------- conv3+conv4 FUSED v4: 8 waves (512 thr), R=2, 2 blocks/CU target ----
// Same math as validated v3; per-wave tile halved for occupancy. LDS 64KB.
__global__ __launch_bounds__(512, 4) void conv34_fused4(
    const __half* __restrict__ X, const __half* __restrict__ Bt,
    const float* __restrict__ bias3, const __half* __restrict__ W4m,
    const float* __restrict__ bias4, float* __restrict__ out) {
    constexpr int CIN = 64, HIN = 16, HH = 256, KTOT = 256;
    constexpr int SL = 8, T = 512, AROWS = 256, AH = AROWS * CIN;  // 16384 halves
    constexpr int BH = 32 * KTOT;                                  // 8192 halves
    constexpr int PS = 1164;
    __shared__ _Float16 lds[AH + 2 * BH];   // 65,536 B

    int tid = threadIdx.x;
    int lane = tid & 63, w = tid >> 6;      // w in 0..7
    int kg = lane >> 4, coll = lane & 15;
    int n = blockIdx.x;
    int posbase = w * 32;

    // ---- stage A (whole 16x16x64 image) ----
    const __half* Xs = X + (size_t)n * HH * CIN;
    #pragma unroll
    for (int q = 0; q < 4; ++q) {
        int i = tid + q * T;
        int row = i / SL, slot = i % SL;
        f16x8 v = *(const f16x8*)(Xs + (size_t)i * 8);
        *(f16x8*)(&lds[row * CIN + ((slot ^ (row & 7)) * 8)]) = v;
    }
    // ---- stage B for parity 0 into buffer 0 ----
    #pragma unroll
    for (int q = 0; q < 2; ++q) {
        int i = tid + q * T;
        int o = i >> 5, sl = i & 31;
        f16x8 b0 = *(const f16x8*)(Bt + (size_t)o * KTOT + sl * 8);
        *(f16x8*)(&lds[AH + o * KTOT + ((sl ^ (o & 7)) * 8)]) = b0;
    }
    __syncthreads();

    int posl[2]; bool okr[2][3], okc[2][3];
    #pragma unroll
    for (int r = 0; r < 2; ++r) {
        int p = posbase + r * 16 + coll;
        posl[r] = p;
        int a = p >> 4, b = p & 15;
        #pragma unroll
        for (int s = 0; s < 3; ++s) {
            okr[r][s] = (unsigned)(a + s - 1) < (unsigned)HIN;
            okc[r][s] = (unsigned)(b + s - 1) < (unsigned)HIN;
        }
    }

    f32x4 ib[2];
    #pragma unroll
    for (int f = 0; f < 2; ++f)
        #pragma unroll
        for (int g = 0; g < 4; ++g) ib[f][g] = bias3[f * 16 + kg * 4 + g];

    f32x4 acc[4][2][2];
    #pragma unroll
    for (int par = 0; par < 4; ++par)
        #pragma unroll
        for (int r = 0; r < 2; ++r) {
            acc[par][r][0] = ib[0];
            acc[par][r][1] = ib[1];
        }

    // ---- conv3: 4 per-parity stages ----
    f16x8 breg[2];
    #pragma unroll
    for (int par = 0; par < 4; ++par) {
        const int pi = par & 1, pj = par >> 1;
        const int buf = par & 1;
        if (par < 3) {
            #pragma unroll
            for (int q = 0; q < 2; ++q) {
                int i = tid + q * T;
                int o = i >> 5, sl = i & 31;
                breg[q] = *(const f16x8*)(Bt + ((size_t)((par + 1) * 32 + o) * KTOT) + sl * 8);
            }
        }
        const _Float16* Bl = &lds[AH + buf * BH];
        #pragma unroll
        for (int tap = 0; tap < 4; ++tap) {
            const int iu = (tap >> 1) + pi, iv = (tap & 1) + pj;
            const int delta = (iu - 1) * HIN + (iv - 1);
            int rp[2]; bool ok[2];
            #pragma unroll
            for (int r = 0; r < 2; ++r) {
                int t2 = posl[r] + delta;
                rp[r] = min(max(t2, 0), AROWS - 1);
                ok[r] = okr[r][iu] && okc[r][iv];
            }
            #pragma unroll
            for (int cc = 0; cc < 2; ++cc) {
                const int slA = cc * 4 + kg;
                const int slB = tap * 8 + slA;
                f16x8 b[2];
                #pragma unroll
                for (int f = 0; f < 2; ++f)
                    b[f] = *(const f16x8*)(&Bl[(f * 16 + coll) * KTOT +
                                               ((slB ^ (coll & 7)) * 8)]);
                f16x8 a[2];
                #pragma unroll
                for (int r = 0; r < 2; ++r) {
                    f16x8 v = *(const f16x8*)(&lds[rp[r] * CIN +
                                                   ((slA ^ (rp[r] & 7)) * 8)]);
                    a[r] = ok[r] ? v : (f16x8){0, 0, 0, 0, 0, 0, 0, 0};
                }
                #pragma unroll
                for (int r = 0; r < 2; ++r)
                    #pragma unroll
                    for (int f = 0; f < 2; ++f)
                        acc[par][r][f] = __builtin_amdgcn_mfma_f32_16x16x32_f16(
                            b[f], a[r], acc[par][r][f], 0, 0, 0);
            }
        }
        if (par < 3) {
            #pragma unroll
            for (int q = 0; q < 2; ++q) {
                int i = tid + q * T;
                int o = i >> 5, sl = i & 31;
                *(f16x8*)(&lds[AH + ((par + 1) & 1) * BH + o * KTOT +
                               ((sl ^ (o & 7)) * 8)]) = breg[q];
            }
            __syncthreads();
        }
    }
    __syncthreads();

    // ---- conv4 phase (MFMA, merged shifts) ----
    int a_base = w * 4;
    int lane_base = a_base * 34 + coll;
    float bv4 = bias4[0];
    f32x4 acc4[8];
    #pragma unroll
    for (int g2 = 0; g2 < 8; ++g2) acc4[g2] = (f32x4){bv4, bv4, bv4, bv4};

    #pragma unroll
    for (int f = 0; f < 2; ++f) {
        for (int i = tid; i < 264; i += T) {
            int posi = i >> 1, q = i & 1;
            int rr, sc;
            if (posi < 68) { rr = (posi < 34) ? 0 : 33; sc = posi % 34; }
            else { int e = posi - 68; rr = 1 + (e >> 1); sc = (e & 1) ? 33 : 0; }
            int site = rr * 34 + sc;
            int ss = site ^ ((site >> 3) & 7);
            *(f16x8*)(&lds[(q * PS + ss) * 8]) = (f16x8){0, 0, 0, 0, 0, 0, 0, 0};
        }
        #pragma unroll
        for (int par = 0; par < 4; ++par) {
            const int pi = par & 1, pj = par >> 1;
            #pragma unroll
            for (int r = 0; r < 2; ++r) {
                int p = posl[r];
                int a2 = p >> 4, b2 = p & 15;
                int site = (2 * a2 + pi + 1) * 34 + (2 * b2 + pj + 1);
                int ss = site ^ ((site >> 3) & 7);
                f16x4 pv;
                #pragma unroll
                for (int g = 0; g < 4; ++g) {
                    float v = acc[par][r][f][g];
                    v = v > 0.f ? v : 0.f;
                    pv[g] = (_Float16)v;
                }
                *(f16x4*)(&lds[((kg >> 1) * PS + ss) * 8 + (kg & 1) * 4]) = pv;
            }
        }
        __syncthreads();
        #pragma unroll
        for (int sp = 0; sp < 5; ++sp) {
            f16x8 aw = *(const f16x8*)(W4m + ((size_t)(f * 5 + sp) * 16 + coll) * 32 + kg * 8);
            int s01 = sp * 2 + (kg >> 1);
            int bs = (s01 >= 9) ? 0 : (s01 / 3) * 34 + (s01 % 3);
            int lb = lane_base + bs;
            #pragma unroll
            for (int g2 = 0; g2 < 8; ++g2) {
                int a_loc = g2 >> 1, bh = g2 & 1;
                int site = lb + a_loc * 34 + bh * 16;
                int ss = site ^ ((site >> 3) & 7);
                f16x8 bx = *(const f16x8*)(&lds[((kg & 1) * PS + ss) * 8]);
                acc4[g2] = __builtin_amdgcn_mfma_f32_16x16x32_f16(aw, bx, acc4[g2], 0, 0, 0);
            }
        }
        if (f == 0) __syncthreads();
    }
    if (kg == 0) {
        #pragma unroll
        for (int g2 = 0; g2 < 8; ++g2) {
            int a = a_base + (g2 >> 1);
            int bcol = (g2 & 1) * 32 + 2 * coll;
            float2 v0 = {acc4[g2][0], acc4[g2][2]};
            float2 v1 = {acc4[g2][1], acc4[g2][3]};
            *(float2*)(&out[((size_t)n * 64 + 2 * a) * 64 + bcol]) = v0;
            *(float2*)(&out[((size_t)n * 64 + 2 * a + 1) * 64 + bcol]) = v1;
        }
    }
}

// ---------------- launch -----------------------------------------------------
extern "C" void kernel_launch(void* const* d_in, const int* in_sizes, int n_in,
                              void* d_out, int out_size, void* d_ws, size_t ws_size,
                              hipStream_t stream) {
    const float* angles   = (const float*)d_in[0];
    const float* item_rep = (const float*)d_in[1];
    const float* W        = (const float*)d_in[2];
    const float* bfc      = (const float*)d_in[3];
    const float* k1       = (const float*)d_in[4];
    const float* b1       = (const float*)d_in[5];
    const float* k2       = (const float*)d_in[6];
    const float* b2       = (const float*)d_in[7];
    const float* k3       = (const float*)d_in[8];
    const float* b3       = (const float*)d_in[9];
    const float* k4       = (const float*)d_in[10];
    const float* b4       = (const float*)d_in[11];

    char* ws = (char*)d_ws;
    float*  Ctab  = (float*)(ws + 0);                 //  32 KB
    __half* itemh = (__half*)(ws + 32768);            //   2 MB
    __half* Bt1   = (__half*)(ws + 2129920);          //   1 MB
    __half* Bt2   = (__half*)(ws + 3178496);          // 256 KB
    __half* Bt3   = (__half*)(ws + 3440640);          //  64 KB
    __half* W4m   = (__half*)(ws + 3506176);          //  10 KB
    __half* x0    = (__half*)(ws + 4194304);          //  16 MB -> 20,971,520
    __half* x1    = (__half*)(ws + 20971520);         //  32 MB -> 54,525,952
    __half* Wtfc  = (__half*)(ws + 121634816);        //   4 MB (dead region reuse)
    __half* x2    = (__half*)(ws + 155713536);        //  64 MB -> 222,822,400
    float*  out   = (float*)d_out;

    coef_kernel<<<1, 512, 0, stream>>>(Ctab);
    wigner_kernel<<<NBATCH, 64, 0, stream>>>(angles, item_rep, Ctab, itemh);
    fcw_prep2<<<dim3(KPAD / 64, HID / 64), 256, 0, stream>>>(W, Wtfc);
    convw_prep<256, 128><<<16, 256, 0, stream>>>(k1, Bt1);
    convw_prep<128, 64><<<16, 256, 0, stream>>>(k2, Bt2);
    convw_prep<64, 32><<<16, 256, 0, stream>>>(k3, Bt3);
    w4m_prep<<<20, 256, 0, stream>>>(k4, W4m);

    // FC: 2048x512 @ 512x4096 -> x0
    fc_mfma<<<dim3(16, 32), 256, 0, stream>>>(itemh, Wtfc, bfc, x0);
    // conv1: 4x4x256 -> 8x8x128  (R=1, CF=4, y=2 slices, k-split B stages)
    convt_lds3<256, 128, 4, 1, 2, 4, 4, 2, 8, 0><<<dim3(512, 2), 256, 0, stream>>>(x0, Bt1, b1, x1);
    // conv2: 8x8x128 -> 16x16x64 (8 waves, R=1, CF=4) LDS = 64KB
    convt_lds3<128, 64, 8, 1, 3, 4, 8, 1, 16, 0><<<dim3(1024, 1), 512, 0, stream>>>(x1, Bt2, b2, x2);
    // conv3+conv4 fused v4 (8 waves, R=2): 16x16x64 -> (LDS) -> 64x64x1
    conv34_fused4<<<NBATCH, 512, 0, stream>>>(x2, Bt3, b3, W4m, b4, out);
}